// Round 1
// baseline (606.569 us; speedup 1.0000x reference)
//
#include <hip/hip_runtime.h>

// Problem constants
#define N_NODES 50000
#define N_EDGES 800000
#define NFEAT 512
#define NHID 256
#define NCLASS 64
#define NCOMB 576           // NHID + NHID + NCLASS  (xw1 | a_skip0 | a_skip1)
#define RRELU_SLOPE 0.2291666666666667f

typedef __attribute__((ext_vector_type(8))) short bf16x8;
typedef __attribute__((ext_vector_type(4))) float f32x4;

// fp32 -> bf16 (RNE), raw bits
__device__ __forceinline__ unsigned short f2bf(float f) {
    unsigned int x = __float_as_uint(f);
    unsigned int r = (x + 0x7fffu + ((x >> 16) & 1u)) >> 16;
    return (unsigned short)r;
}

// ---------------- cast fp32 -> bf16, 4 elems/thread ----------------
__global__ void cast_f32_bf16x4(const float* __restrict__ in,
                                unsigned short* __restrict__ out, long n4) {
    long i = (long)blockIdx.x * blockDim.x + threadIdx.x;
    long stride = (long)gridDim.x * blockDim.x;
    for (; i < n4; i += stride) {
        float4 v = ((const float4*)in)[i];
        ushort4 o;
        o.x = f2bf(v.x); o.y = f2bf(v.y); o.z = f2bf(v.z); o.w = f2bf(v.w);
        ((ushort4*)out)[i] = o;
    }
}

// ---------------- pack B = [w1 | w2 | w4] (bf16) + bias = [0 | b2 | b4] ----------------
__global__ void pack_B(const float* __restrict__ w1, const float* __restrict__ w2,
                       const float* __restrict__ w4, const float* __restrict__ b2,
                       const float* __restrict__ b4,
                       unsigned short* __restrict__ Bb, float* __restrict__ biasb) {
    int i = blockIdx.x * blockDim.x + threadIdx.x;
    const int total = NFEAT * NCOMB;
    if (i < total) {
        int k = i / NCOMB, c = i - k * NCOMB;
        float v;
        if (c < NHID)            v = w1[k * NHID + c];
        else if (c < 2 * NHID)   v = w2[k * NHID + (c - NHID)];
        else                     v = w4[k * NCLASS + (c - 2 * NHID)];
        Bb[i] = f2bf(v);
    }
    if (i < NCOMB) {
        biasb[i] = (i < NHID) ? 0.f : (i < 2 * NHID ? b2[i - NHID] : b4[i - 2 * NHID]);
    }
}

// ---------------- row_ptr from sorted COO rows (binary search per node) ----------------
__global__ void build_rowptr(const int* __restrict__ erow, int* __restrict__ rp,
                             int n_nodes, int n_edges) {
    int n = blockIdx.x * blockDim.x + threadIdx.x;
    if (n > n_nodes) return;
    int lo = 0, hi = n_edges;
    while (lo < hi) {
        int mid = (lo + hi) >> 1;
        if (erow[mid] < n) lo = mid + 1; else hi = mid;
    }
    rp[n] = lo;
}

// ---------------- bf16 MFMA GEMM: C[M,NC] = A[M,K] @ B[K,NC] (+bias) ----------------
// Tile: 64x64 block (4 waves, each 32x32 via 2x2 of 16x16x32 MFMA), BK=32.
#define BM 64
#define BN 64
#define BK 32
#define ASTRIDE 40   // 32 + 8 pad (bf16 elems); rows stay 16B-aligned (80B)

__global__ __launch_bounds__(256)
void gemm_bf16(const unsigned short* __restrict__ A, const unsigned short* __restrict__ B,
               const float* __restrict__ bias, float* __restrict__ C,
               int M, int K, int NC) {
    __shared__ unsigned short As[BM * ASTRIDE];
    __shared__ unsigned short Bs[BN * ASTRIDE];
    const int tid  = threadIdx.x;
    const int row0 = blockIdx.x * BM;
    const int col0 = blockIdx.y * BN;
    const int lane = tid & 63;
    const int wave = tid >> 6;
    const int wr = (wave >> 1) * 32;      // wave row offset in tile
    const int wc = (wave & 1) * 32;       // wave col offset in tile
    const int lm = lane & 15;             // row (A) / col (B,C) within 16
    const int lk = (lane >> 4) * 8;       // k-octet base

    // staging indices
    const int am = tid >> 2;              // 0..63  (A row)
    const int ak = (tid & 3) * 8;         // 0,8,16,24
    const int bk = tid >> 3;              // 0..31  (B k-row)
    const int bn = (tid & 7) * 8;         // 0..56  (B col octet)

    f32x4 acc[2][2] = {};

    for (int k0 = 0; k0 < K; k0 += BK) {
        // stage A tile (row-major, guarded rows -> zeros)
        uint4 av = {0u, 0u, 0u, 0u};
        int gm = row0 + am;
        if (gm < M) av = *(const uint4*)(A + (size_t)gm * K + k0 + ak);
        *(uint4*)(As + am * ASTRIDE + ak) = av;
        // stage B tile transposed: Bs[n][k]
        uint4 bv = *(const uint4*)(B + (size_t)(k0 + bk) * NC + col0 + bn);
        const unsigned short* bs = (const unsigned short*)&bv;
        #pragma unroll
        for (int j = 0; j < 8; ++j)
            Bs[(bn + j) * ASTRIDE + bk] = bs[j];
        __syncthreads();

        bf16x8 af0 = *(const bf16x8*)(As + (wr + lm) * ASTRIDE + lk);
        bf16x8 af1 = *(const bf16x8*)(As + (wr + 16 + lm) * ASTRIDE + lk);
        bf16x8 bf0 = *(const bf16x8*)(Bs + (wc + lm) * ASTRIDE + lk);
        bf16x8 bf1 = *(const bf16x8*)(Bs + (wc + 16 + lm) * ASTRIDE + lk);
        acc[0][0] = __builtin_amdgcn_mfma_f32_16x16x32_bf16(af0, bf0, acc[0][0], 0, 0, 0);
        acc[0][1] = __builtin_amdgcn_mfma_f32_16x16x32_bf16(af0, bf1, acc[0][1], 0, 0, 0);
        acc[1][0] = __builtin_amdgcn_mfma_f32_16x16x32_bf16(af1, bf0, acc[1][0], 0, 0, 0);
        acc[1][1] = __builtin_amdgcn_mfma_f32_16x16x32_bf16(af1, bf1, acc[1][1], 0, 0, 0);
        __syncthreads();
    }

    // epilogue: C/D layout col=lane&15, row=(lane>>4)*4+reg
    #pragma unroll
    for (int i = 0; i < 2; ++i) {
        #pragma unroll
        for (int j = 0; j < 2; ++j) {
            int col = col0 + wc + j * 16 + lm;
            float bvv = bias ? bias[col] : 0.f;
            #pragma unroll
            for (int r = 0; r < 4; ++r) {
                int row = row0 + wr + i * 16 + (lane >> 4) * 4 + r;
                if (row < M) C[(size_t)row * NC + col] = acc[i][j][r] + bvv;
            }
        }
    }
}

// ---------------- SpMM1 + bias + skip + RReLU -> h (bf16) ----------------
// one block per node, 256 threads = 256 features
__global__ __launch_bounds__(256)
void spmm1_rrelu(const int* __restrict__ rp, const int* __restrict__ ecol,
                 const float* __restrict__ eval, const float* __restrict__ fused,
                 const float* __restrict__ b1, unsigned short* __restrict__ hb) {
    int n = blockIdx.x;
    int f = threadIdx.x;
    int lo = rp[n], hi = rp[n + 1];
    float s = 0.f;
    for (int e = lo; e < hi; ++e) {
        int c = ecol[e];
        float v = eval[e];
        s += v * fused[(size_t)c * NCOMB + f];
    }
    float val = s + b1[f] + fused[(size_t)n * NCOMB + NHID + f];
    val = (val >= 0.f) ? val : val * RRELU_SLOPE;
    hb[(size_t)n * NHID + f] = f2bf(val);
}

// ---------------- SpMM2 + b3 + skip -> out ----------------
// 4 nodes per block (one wave each), 64 features per node
__global__ __launch_bounds__(256)
void spmm2_out(const int* __restrict__ rp, const int* __restrict__ ecol,
               const float* __restrict__ eval, const float* __restrict__ hw3,
               const float* __restrict__ b3, const float* __restrict__ fused,
               float* __restrict__ out, int n_nodes) {
    int n = blockIdx.x * 4 + (threadIdx.x >> 6);
    int f = threadIdx.x & 63;
    if (n >= n_nodes) return;
    int lo = rp[n], hi = rp[n + 1];
    float s = 0.f;
    for (int e = lo; e < hi; ++e) {
        s += eval[e] * hw3[(size_t)ecol[e] * NCLASS + f];
    }
    out[(size_t)n * NCLASS + f] = s + b3[f] + fused[(size_t)n * NCOMB + 2 * NHID + f];
}

extern "C" void kernel_launch(void* const* d_in, const int* in_sizes, int n_in,
                              void* d_out, int out_size, void* d_ws, size_t ws_size,
                              hipStream_t stream) {
    const float* x    = (const float*)d_in[0];
    const int*   erow = (const int*)d_in[1];
    const int*   ecol = (const int*)d_in[2];
    const float* ev   = (const float*)d_in[3];
    const float* w1   = (const float*)d_in[4];
    const float* b1   = (const float*)d_in[5];
    const float* w2   = (const float*)d_in[6];
    const float* b2   = (const float*)d_in[7];
    const float* w3   = (const float*)d_in[8];
    const float* b3   = (const float*)d_in[9];
    const float* w4   = (const float*)d_in[10];
    const float* b4   = (const float*)d_in[11];
    float* out = (float*)d_out;

    char* ws = (char*)d_ws;
    size_t off = 0;
    auto alloc = [&](size_t bytes) -> void* {
        off = (off + 255) & ~(size_t)255;
        void* p = ws + off;
        off += bytes;
        return p;
    };

    unsigned short* xb    = (unsigned short*)alloc((size_t)N_NODES * NFEAT * 2);
    unsigned short* Bb    = (unsigned short*)alloc((size_t)NFEAT * NCOMB * 2);
    float*          biasb = (float*)alloc(NCOMB * 4);
    float*          fused = (float*)alloc((size_t)N_NODES * NCOMB * 4);
    unsigned short* hb    = (unsigned short*)alloc((size_t)N_NODES * NHID * 2);
    unsigned short* w3b   = (unsigned short*)alloc((size_t)NHID * NCLASS * 2);
    float*          hw3   = (float*)alloc((size_t)N_NODES * NCLASS * 4);
    int*            rp    = (int*)alloc((size_t)(N_NODES + 1) * 4);

    // 1) casts & packing
    cast_f32_bf16x4<<<4096, 256, 0, stream>>>(x, xb, (long)N_NODES * NFEAT / 4);
    cast_f32_bf16x4<<<16, 256, 0, stream>>>(w3, w3b, (long)NHID * NCLASS / 4);
    pack_B<<<(NFEAT * NCOMB + 255) / 256, 256, 0, stream>>>(w1, w2, w4, b2, b4, Bb, biasb);
    build_rowptr<<<(N_NODES + 1 + 255) / 256, 256, 0, stream>>>(erow, rp, N_NODES, N_EDGES);

    // 2) fused GEMM: [xw1 | a_skip0 | a_skip1] = xb @ [w1|w2|w4] + [0|b2|b4]
    dim3 g1((N_NODES + BM - 1) / BM, NCOMB / BN);
    gemm_bf16<<<g1, 256, 0, stream>>>(xb, Bb, biasb, fused, N_NODES, NFEAT, NCOMB);

    // 3) spmm(xw1) + b1 + a_skip0 -> rrelu -> hb (bf16)
    spmm1_rrelu<<<N_NODES, 256, 0, stream>>>(rp, ecol, ev, fused, b1, hb);

    // 4) hw3 = hb @ w3
    dim3 g2((N_NODES + BM - 1) / BM, NCLASS / BN);
    gemm_bf16<<<g2, 256, 0, stream>>>(hb, w3b, nullptr, hw3, N_NODES, NHID, NCLASS);

    // 5) out = spmm(hw3) + b3 + a_skip1
    spmm2_out<<<(N_NODES + 3) / 4, 256, 0, stream>>>(rp, ecol, ev, hw3, b3, fused, out, N_NODES);

    // 6) tuple outputs 1..4 = unchanged weights
    size_t o = (size_t)N_NODES * NCLASS;
    hipMemcpyAsync(out + o, w1, (size_t)NFEAT * NHID * 4, hipMemcpyDeviceToDevice, stream);
    o += (size_t)NFEAT * NHID;
    hipMemcpyAsync(out + o, w2, (size_t)NFEAT * NHID * 4, hipMemcpyDeviceToDevice, stream);
    o += (size_t)NFEAT * NHID;
    hipMemcpyAsync(out + o, w3, (size_t)NHID * NCLASS * 4, hipMemcpyDeviceToDevice, stream);
    o += (size_t)NHID * NCLASS;
    hipMemcpyAsync(out + o, w4, (size_t)NFEAT * NCLASS * 4, hipMemcpyDeviceToDevice, stream);
}

// Round 2
// 428.158 us; speedup vs baseline: 1.4167x; 1.4167x over previous
//
#include <hip/hip_runtime.h>

// Problem constants
#define N_NODES 50000
#define N_EDGES 800000
#define NFEAT 512
#define NHID 256
#define NCLASS 64
#define NCOMB 576
#define NSKIP 320            // NHID + NCLASS (skip0 | skip1), fp32
#define RRELU_SLOPE 0.2291666666666667f

typedef __attribute__((ext_vector_type(8))) short bf16x8;
typedef __attribute__((ext_vector_type(4))) float f32x4;

// fp32 -> bf16 (RNE), raw bits
__device__ __forceinline__ unsigned short f2bf(float f) {
    unsigned int x = __float_as_uint(f);
    unsigned int r = (x + 0x7fffu + ((x >> 16) & 1u)) >> 16;
    return (unsigned short)r;
}
__device__ __forceinline__ float bf2f(unsigned short u) {
    return __uint_as_float(((unsigned int)u) << 16);
}
__device__ __forceinline__ float bf_lo(unsigned int u) { return __uint_as_float(u << 16); }
__device__ __forceinline__ float bf_hi(unsigned int u) { return __uint_as_float(u & 0xffff0000u); }

// ---------------- cast fp32 -> bf16, 4 elems/thread ----------------
__global__ void cast_f32_bf16x4(const float* __restrict__ in,
                                unsigned short* __restrict__ out, long n4) {
    long i = (long)blockIdx.x * blockDim.x + threadIdx.x;
    long stride = (long)gridDim.x * blockDim.x;
    for (; i < n4; i += stride) {
        float4 v = ((const float4*)in)[i];
        ushort4 o;
        o.x = f2bf(v.x); o.y = f2bf(v.y); o.z = f2bf(v.z); o.w = f2bf(v.w);
        ((ushort4*)out)[i] = o;
    }
}

// ---------------- pack Bt = [w1|w2|w4]^T as [NCOMB, NFEAT] bf16; bias [NCOMB] ------
__global__ void pack_Bt(const float* __restrict__ w1, const float* __restrict__ w2,
                        const float* __restrict__ w4, const float* __restrict__ b2,
                        const float* __restrict__ b4,
                        unsigned short* __restrict__ Bt, float* __restrict__ biasb) {
    int i = blockIdx.x * blockDim.x + threadIdx.x;
    const int total = NFEAT * NCOMB;
    if (i < total) {
        int c = i >> 9;            // NFEAT=512
        int k = i & 511;
        float v;
        if (c < NHID)            v = w1[k * NHID + c];
        else if (c < 2 * NHID)   v = w2[k * NHID + (c - NHID)];
        else                     v = w4[k * NCLASS + (c - 2 * NHID)];
        Bt[i] = f2bf(v);
    }
    if (i < NCOMB) {
        biasb[i] = (i < NHID) ? 0.f : (i < 2 * NHID ? b2[i - NHID] : b4[i - 2 * NHID]);
    }
}

// ---------------- pack w3t [NCLASS, NHID] bf16 ----------------
__global__ void pack_w3t(const float* __restrict__ w3, unsigned short* __restrict__ w3t) {
    int i = blockIdx.x * blockDim.x + threadIdx.x;
    if (i < NCLASS * NHID) {
        int c = i >> 8;            // NHID=256
        int k = i & 255;
        w3t[i] = f2bf(w3[k * NCLASS + c]);
    }
}

// ---------------- row_ptr from sorted COO rows ----------------
__global__ void build_rowptr(const int* __restrict__ erow, int* __restrict__ rp,
                             int n_nodes, int n_edges) {
    int n = blockIdx.x * blockDim.x + threadIdx.x;
    if (n > n_nodes) return;
    int lo = 0, hi = n_edges;
    while (lo < hi) {
        int mid = (lo + hi) >> 1;
        if (erow[mid] < n) lo = mid + 1; else hi = mid;
    }
    rp[n] = lo;
}

// ---------------- bf16 MFMA GEMM ----------------
// Tile 128x64, BK=64, 4 waves each computing 64x32 (4x2 of 16x16x32 MFMA).
// mode 0: fused-output (cols<256 -> xw1b bf16; cols>=256 -> skipb fp32 + bias)
// mode 1: plain bf16 output to Cout [M, NC]
#define GBM 128
#define GBN 64
#define GBK 64
#define LSTRIDE 72   // 64 + 8 pad elems; 144B rows keep 16B alignment

__global__ __launch_bounds__(256)
void gemm_bf16(const unsigned short* __restrict__ A,   // [M,K] bf16 row-major
               const unsigned short* __restrict__ Bt,  // [NC,K] bf16 row-major (B^T)
               const float* __restrict__ bias,         // [NC] (mode 0)
               unsigned short* __restrict__ Cout,      // mode 1 output
               float* __restrict__ skipb,              // mode 0
               unsigned short* __restrict__ xw1b,      // mode 0
               int M, int K, int NC, int mode) {
    __shared__ unsigned short As[GBM * LSTRIDE];
    __shared__ unsigned short Bs[GBN * LSTRIDE];
    const int tid  = threadIdx.x;
    const int lane = tid & 63;
    const int wave = tid >> 6;
    const int row0 = blockIdx.x * GBM;
    const int col0 = blockIdx.y * GBN;
    const int wr = (wave >> 1) * 64;
    const int wc = (wave & 1) * 32;
    const int lm = lane & 15;
    const int lk = (lane >> 4) * 8;

    f32x4 acc[4][2] = {};

    for (int k0 = 0; k0 < K; k0 += GBK) {
        // stage A: 128x64 bf16, 4 passes of uint4 per thread
        #pragma unroll
        for (int p = 0; p < 4; ++p) {
            int idx = p * 256 + tid;
            int r = idx >> 3;
            int c = (idx & 7) * 8;
            uint4 v = {0u, 0u, 0u, 0u};
            int gr = row0 + r;
            if (gr < M) v = *(const uint4*)(A + (size_t)gr * K + k0 + c);
            *(uint4*)(As + r * LSTRIDE + c) = v;
        }
        // stage B: 64x64 bf16, 2 passes
        #pragma unroll
        for (int p = 0; p < 2; ++p) {
            int idx = p * 256 + tid;
            int r = idx >> 3;
            int c = (idx & 7) * 8;
            uint4 v = *(const uint4*)(Bt + (size_t)(col0 + r) * K + k0 + c);
            *(uint4*)(Bs + r * LSTRIDE + c) = v;
        }
        __syncthreads();

        #pragma unroll
        for (int kk = 0; kk < GBK; kk += 32) {
            bf16x8 bfr[2];
            #pragma unroll
            for (int j = 0; j < 2; ++j)
                bfr[j] = *(const bf16x8*)(Bs + (wc + j * 16 + lm) * LSTRIDE + kk + lk);
            #pragma unroll
            for (int i = 0; i < 4; ++i) {
                bf16x8 af = *(const bf16x8*)(As + (wr + i * 16 + lm) * LSTRIDE + kk + lk);
                acc[i][0] = __builtin_amdgcn_mfma_f32_16x16x32_bf16(af, bfr[0], acc[i][0], 0, 0, 0);
                acc[i][1] = __builtin_amdgcn_mfma_f32_16x16x32_bf16(af, bfr[1], acc[i][1], 0, 0, 0);
            }
        }
        __syncthreads();
    }

    // epilogue: C/D layout col=lane&15, row=(lane>>4)*4+reg
    #pragma unroll
    for (int i = 0; i < 4; ++i) {
        #pragma unroll
        for (int j = 0; j < 2; ++j) {
            int col = col0 + wc + j * 16 + lm;
            #pragma unroll
            for (int r = 0; r < 4; ++r) {
                int row = row0 + wr + i * 16 + (lane >> 4) * 4 + r;
                if (row < M) {
                    float v = acc[i][j][r];
                    if (mode == 0) {
                        if (col < NHID) xw1b[(size_t)row * NHID + col] = f2bf(v);
                        else            skipb[(size_t)row * NSKIP + (col - NHID)] = v + bias[col];
                    } else {
                        Cout[(size_t)row * NC + col] = f2bf(v);
                    }
                }
            }
        }
    }
}

// ---------------- SpMM1 + b1 + skip0 + RReLU -> hb (bf16) ----------------
// one wave per node (4 nodes/block); lane handles 4 features via uint2 (8B) loads
__global__ __launch_bounds__(256)
void spmm1_rrelu(const int* __restrict__ rp, const int* __restrict__ ecol,
                 const float* __restrict__ eval, const unsigned short* __restrict__ xw1b,
                 const float* __restrict__ skipb, const float* __restrict__ b1,
                 unsigned short* __restrict__ hb, int n_nodes) {
    int n = blockIdx.x * 4 + (threadIdx.x >> 6);
    if (n >= n_nodes) return;
    int lane = threadIdx.x & 63;
    int f = lane * 4;
    int lo = rp[n], hi = rp[n + 1];
    float s0 = 0.f, s1 = 0.f, s2 = 0.f, s3 = 0.f;
    int e = lo;
    for (; e + 1 < hi; e += 2) {
        int   ca = ecol[e],     cb = ecol[e + 1];
        float va = eval[e],     vb = eval[e + 1];
        uint2 pa = *(const uint2*)(xw1b + (size_t)ca * NHID + f);
        uint2 pb = *(const uint2*)(xw1b + (size_t)cb * NHID + f);
        s0 += va * bf_lo(pa.x) + vb * bf_lo(pb.x);
        s1 += va * bf_hi(pa.x) + vb * bf_hi(pb.x);
        s2 += va * bf_lo(pa.y) + vb * bf_lo(pb.y);
        s3 += va * bf_hi(pa.y) + vb * bf_hi(pb.y);
    }
    if (e < hi) {
        int   c = ecol[e];
        float v = eval[e];
        uint2 p = *(const uint2*)(xw1b + (size_t)c * NHID + f);
        s0 += v * bf_lo(p.x);
        s1 += v * bf_hi(p.x);
        s2 += v * bf_lo(p.y);
        s3 += v * bf_hi(p.y);
    }
    float4 sk = *(const float4*)(skipb + (size_t)n * NSKIP + f);
    float4 bb = *(const float4*)(b1 + f);
    float v0 = s0 + bb.x + sk.x;
    float v1 = s1 + bb.y + sk.y;
    float v2 = s2 + bb.z + sk.z;
    float v3 = s3 + bb.w + sk.w;
    v0 = (v0 >= 0.f) ? v0 : v0 * RRELU_SLOPE;
    v1 = (v1 >= 0.f) ? v1 : v1 * RRELU_SLOPE;
    v2 = (v2 >= 0.f) ? v2 : v2 * RRELU_SLOPE;
    v3 = (v3 >= 0.f) ? v3 : v3 * RRELU_SLOPE;
    ushort4 o;
    o.x = f2bf(v0); o.y = f2bf(v1); o.z = f2bf(v2); o.w = f2bf(v3);
    *(ushort4*)(hb + (size_t)n * NHID + f) = o;
}

// ---------------- SpMM2 + b3 + skip1 -> out ----------------
// one wave per node (4 nodes/block); lane = feature (64)
__global__ __launch_bounds__(256)
void spmm2_out(const int* __restrict__ rp, const int* __restrict__ ecol,
               const float* __restrict__ eval, const unsigned short* __restrict__ hw3b,
               const float* __restrict__ b3, const float* __restrict__ skipb,
               float* __restrict__ out, int n_nodes) {
    int n = blockIdx.x * 4 + (threadIdx.x >> 6);
    if (n >= n_nodes) return;
    int f = threadIdx.x & 63;
    int lo = rp[n], hi = rp[n + 1];
    float s = 0.f;
    int e = lo;
    for (; e + 1 < hi; e += 2) {
        int   ca = ecol[e],   cb = ecol[e + 1];
        float va = eval[e],   vb = eval[e + 1];
        float xa = bf2f(hw3b[(size_t)ca * NCLASS + f]);
        float xb = bf2f(hw3b[(size_t)cb * NCLASS + f]);
        s += va * xa + vb * xb;
    }
    if (e < hi) {
        s += eval[e] * bf2f(hw3b[(size_t)ecol[e] * NCLASS + f]);
    }
    out[(size_t)n * NCLASS + f] = s + b3[f] + skipb[(size_t)n * NSKIP + NHID + f];
}

extern "C" void kernel_launch(void* const* d_in, const int* in_sizes, int n_in,
                              void* d_out, int out_size, void* d_ws, size_t ws_size,
                              hipStream_t stream) {
    const float* x    = (const float*)d_in[0];
    const int*   erow = (const int*)d_in[1];
    const int*   ecol = (const int*)d_in[2];
    const float* ev   = (const float*)d_in[3];
    const float* w1   = (const float*)d_in[4];
    const float* b1   = (const float*)d_in[5];
    const float* w2   = (const float*)d_in[6];
    const float* b2   = (const float*)d_in[7];
    const float* w3   = (const float*)d_in[8];
    const float* b3   = (const float*)d_in[9];
    const float* w4   = (const float*)d_in[10];
    const float* b4   = (const float*)d_in[11];
    float* out = (float*)d_out;

    char* ws = (char*)d_ws;
    size_t off = 0;
    auto alloc = [&](size_t bytes) -> void* {
        off = (off + 255) & ~(size_t)255;
        void* p = ws + off;
        off += bytes;
        return p;
    };

    unsigned short* xb    = (unsigned short*)alloc((size_t)N_NODES * NFEAT * 2);
    unsigned short* Bt    = (unsigned short*)alloc((size_t)NFEAT * NCOMB * 2);
    float*          biasb = (float*)alloc(NCOMB * 4);
    unsigned short* xw1b  = (unsigned short*)alloc((size_t)N_NODES * NHID * 2);
    float*          skipb = (float*)alloc((size_t)N_NODES * NSKIP * 4);
    unsigned short* hb    = (unsigned short*)alloc((size_t)N_NODES * NHID * 2);
    unsigned short* w3t   = (unsigned short*)alloc((size_t)NHID * NCLASS * 2);
    unsigned short* hw3b  = (unsigned short*)alloc((size_t)N_NODES * NCLASS * 2);
    int*            rp    = (int*)alloc((size_t)(N_NODES + 1) * 4);

    // 1) casts & packing
    cast_f32_bf16x4<<<4096, 256, 0, stream>>>(x, xb, (long)N_NODES * NFEAT / 4);
    pack_Bt<<<(NFEAT * NCOMB + 255) / 256, 256, 0, stream>>>(w1, w2, w4, b2, b4, Bt, biasb);
    pack_w3t<<<(NCLASS * NHID + 255) / 256, 256, 0, stream>>>(w3, w3t);
    build_rowptr<<<(N_NODES + 1 + 255) / 256, 256, 0, stream>>>(erow, rp, N_NODES, N_EDGES);

    // 2) fused GEMM: xb @ [w1|w2|w4] -> xw1b (bf16) | skipb (fp32, +bias)
    dim3 g1((N_NODES + GBM - 1) / GBM, NCOMB / GBN);
    gemm_bf16<<<g1, 256, 0, stream>>>(xb, Bt, biasb, nullptr, skipb, xw1b,
                                      N_NODES, NFEAT, NCOMB, 0);

    // 3) spmm(xw1) + b1 + skip0 -> rrelu -> hb (bf16)
    spmm1_rrelu<<<(N_NODES + 3) / 4, 256, 0, stream>>>(rp, ecol, ev, xw1b, skipb, b1, hb, N_NODES);

    // 4) hw3b = hb @ w3 (bf16 out)
    dim3 g2((N_NODES + GBM - 1) / GBM, NCLASS / GBN);
    gemm_bf16<<<g2, 256, 0, stream>>>(hb, w3t, nullptr, hw3b, nullptr, nullptr,
                                      N_NODES, NHID, NCLASS, 1);

    // 5) out = spmm(hw3) + b3 + skip1
    spmm2_out<<<(N_NODES + 3) / 4, 256, 0, stream>>>(rp, ecol, ev, hw3b, b3, skipb, out, N_NODES);

    // 6) tuple outputs 1..4 = unchanged weights
    size_t o = (size_t)N_NODES * NCLASS;
    hipMemcpyAsync(out + o, w1, (size_t)NFEAT * NHID * 4, hipMemcpyDeviceToDevice, stream);
    o += (size_t)NFEAT * NHID;
    hipMemcpyAsync(out + o, w2, (size_t)NFEAT * NHID * 4, hipMemcpyDeviceToDevice, stream);
    o += (size_t)NFEAT * NHID;
    hipMemcpyAsync(out + o, w3, (size_t)NHID * NCLASS * 4, hipMemcpyDeviceToDevice, stream);
    o += (size_t)NHID * NCLASS;
    hipMemcpyAsync(out + o, w4, (size_t)NFEAT * NCLASS * 4, hipMemcpyDeviceToDevice, stream);
}

// Round 3
// 390.260 us; speedup vs baseline: 1.5543x; 1.0971x over previous
//
#include <hip/hip_runtime.h>

// Problem constants
#define N_NODES 50000
#define N_EDGES 800000
#define NFEAT 512
#define NHID 256
#define NCLASS 64
#define NCOMB 576
#define NSKIP 320            // NHID + NCLASS (skip0 | skip1), fp32
#define RRELU_SLOPE 0.2291666666666667f

typedef __attribute__((ext_vector_type(8))) short bf16x8;
typedef __attribute__((ext_vector_type(4))) float f32x4;

// async global->LDS, 16B per lane; dest = wave-uniform base + lane*16
#define GLOAD_LDS16(g, l)                                                      \
    __builtin_amdgcn_global_load_lds(                                          \
        (const __attribute__((address_space(1))) void*)(g),                    \
        (__attribute__((address_space(3))) void*)(l), 16, 0, 0)

__device__ __forceinline__ unsigned short f2bf(float f) {
    unsigned int x = __float_as_uint(f);
    unsigned int r = (x + 0x7fffu + ((x >> 16) & 1u)) >> 16;
    return (unsigned short)r;
}
__device__ __forceinline__ float bf2f(unsigned short u) {
    return __uint_as_float(((unsigned int)u) << 16);
}
__device__ __forceinline__ float bf_lo(unsigned int u) { return __uint_as_float(u << 16); }
__device__ __forceinline__ float bf_hi(unsigned int u) { return __uint_as_float(u & 0xffff0000u); }

// ---------------- cast fp32 -> bf16, 4 elems/thread ----------------
__global__ void cast_f32_bf16x4(const float* __restrict__ in,
                                unsigned short* __restrict__ out, long n4) {
    long i = (long)blockIdx.x * blockDim.x + threadIdx.x;
    long stride = (long)gridDim.x * blockDim.x;
    for (; i < n4; i += stride) {
        float4 v = ((const float4*)in)[i];
        ushort4 o;
        o.x = f2bf(v.x); o.y = f2bf(v.y); o.z = f2bf(v.z); o.w = f2bf(v.w);
        ((ushort4*)out)[i] = o;
    }
}

// -------- pack Bt = [w1|w2|w4]^T as [NCOMB, NFEAT] bf16; bias (b1 folded into skip0, b3 into skip1)
__global__ void pack_Bt(const float* __restrict__ w1, const float* __restrict__ w2,
                        const float* __restrict__ w4, const float* __restrict__ b1,
                        const float* __restrict__ b2, const float* __restrict__ b3,
                        const float* __restrict__ b4,
                        unsigned short* __restrict__ Bt, float* __restrict__ biasb) {
    int i = blockIdx.x * blockDim.x + threadIdx.x;
    const int total = NFEAT * NCOMB;
    if (i < total) {
        int c = i >> 9;            // NFEAT=512
        int k = i & 511;
        float v;
        if (c < NHID)            v = w1[k * NHID + c];
        else if (c < 2 * NHID)   v = w2[k * NHID + (c - NHID)];
        else                     v = w4[k * NCLASS + (c - 2 * NHID)];
        Bt[i] = f2bf(v);
    }
    if (i < NCOMB) {
        float b = 0.f;
        if (i >= NHID && i < 2 * NHID) b = b1[i - NHID] + b2[i - NHID];
        else if (i >= 2 * NHID)        b = b3[i - 2 * NHID] + b4[i - 2 * NHID];
        biasb[i] = b;
    }
}

// ---------------- pack w3t [NCLASS, NHID] bf16 ----------------
__global__ void pack_w3t(const float* __restrict__ w3, unsigned short* __restrict__ w3t) {
    int i = blockIdx.x * blockDim.x + threadIdx.x;
    if (i < NCLASS * NHID) {
        int c = i >> 8;            // NHID=256
        int k = i & 255;
        w3t[i] = f2bf(w3[k * NCLASS + c]);
    }
}

// ---------------- pack edges: (col, val_bits) ----------------
__global__ void pack_edges(const int* __restrict__ ecol, const float* __restrict__ ev,
                           uint2* __restrict__ ep, int n) {
    int i = blockIdx.x * blockDim.x + threadIdx.x;
    if (i < n) {
        uint2 e;
        e.x = (unsigned)ecol[i];
        e.y = __float_as_uint(ev[i]);
        ep[i] = e;
    }
}

// ---------------- row_ptr from sorted COO rows ----------------
__global__ void build_rowptr(const int* __restrict__ erow, int* __restrict__ rp,
                             int n_nodes, int n_edges) {
    int n = blockIdx.x * blockDim.x + threadIdx.x;
    if (n > n_nodes) return;
    int lo = 0, hi = n_edges;
    while (lo < hi) {
        int mid = (lo + hi) >> 1;
        if (erow[mid] < n) lo = mid + 1; else hi = mid;
    }
    rp[n] = lo;
}

// ---------------- bf16 MFMA GEMM ----------------
// Tile 128x64, BK=64. global_load_lds(16B) staging, XOR-octet swizzle (no pad).
// LDS row = 64 bf16 = 128 B = 8 octets of 16 B; octet g of row r stored at slot g^(r&7).
// grid: x = col-block (fastest -> A-panel L2 locality), y = row-panel.
// mode 0: cols<256 -> xw1b bf16; cols>=256 -> skipb fp32 + bias
// mode 1: bf16 output to Cout [M, NC]
#define GBM 128
#define GBN 64
#define GBK 64

__global__ __launch_bounds__(256)
void gemm_bf16(const unsigned short* __restrict__ A,   // [M,K] bf16 row-major
               const unsigned short* __restrict__ Bt,  // [NC,K] bf16 row-major (B^T)
               const float* __restrict__ bias,
               unsigned short* __restrict__ Cout,
               float* __restrict__ skipb,
               unsigned short* __restrict__ xw1b,
               int M, int K, int NC, int mode) {
    __shared__ unsigned short As[GBM * GBK];   // 16 KB
    __shared__ unsigned short Bs[GBN * GBK];   // 8 KB
    const int tid  = threadIdx.x;
    const int lane = tid & 63;
    const int wave = tid >> 6;
    const int col0 = blockIdx.x * GBN;
    const int row0 = blockIdx.y * GBM;
    const int wr = (wave >> 1) * 64;
    const int wc = (wave & 1) * 32;
    const int lm = lane & 15;
    const int l4 = lane >> 4;       // 0..3 (k-octet within 32-k chunk)
    const int sw = lm & 7;          // row-based swizzle key for frag reads

    // staging lane decomposition: 1024 B per wave-issue = 8 rows x 8 octets
    const int sub  = lane >> 3;     // row within 8-row chunk
    const int slot = lane & 7;      // LDS octet slot this lane fills
    const int goct = slot ^ sub;    // global octet to fetch for that slot

    f32x4 acc[4][2] = {};

    for (int k0 = 0; k0 < K; k0 += GBK) {
        // stage A: 16 chunks of 8 rows; 4 per wave
        #pragma unroll
        for (int p = 0; p < 4; ++p) {
            int chunk = wave * 4 + p;
            int gr = row0 + chunk * 8 + sub;
            if (gr > M - 1) gr = M - 1;     // clamp (dup rows only feed unsaved acc)
            GLOAD_LDS16(A + (size_t)gr * K + k0 + goct * 8, As + chunk * 512);
        }
        // stage B: 8 chunks of 8 rows; 2 per wave
        #pragma unroll
        for (int p = 0; p < 2; ++p) {
            int chunk = wave * 2 + p;
            int rb = col0 + chunk * 8 + sub;
            GLOAD_LDS16(Bt + (size_t)rb * K + k0 + goct * 8, Bs + chunk * 512);
        }
        __syncthreads();

        #pragma unroll
        for (int kk8 = 0; kk8 < GBK / 8; kk8 += 4) {   // two 32-k steps
            const int so = ((kk8 + l4) ^ sw) * 8;
            bf16x8 bfr[2];
            #pragma unroll
            for (int j = 0; j < 2; ++j)
                bfr[j] = *(const bf16x8*)(Bs + (wc + j * 16 + lm) * 64 + so);
            #pragma unroll
            for (int i = 0; i < 4; ++i) {
                bf16x8 af = *(const bf16x8*)(As + (wr + i * 16 + lm) * 64 + so);
                acc[i][0] = __builtin_amdgcn_mfma_f32_16x16x32_bf16(af, bfr[0], acc[i][0], 0, 0, 0);
                acc[i][1] = __builtin_amdgcn_mfma_f32_16x16x32_bf16(af, bfr[1], acc[i][1], 0, 0, 0);
            }
        }
        __syncthreads();
    }

    // epilogue: C/D layout col=lane&15, row=(lane>>4)*4+reg
    #pragma unroll
    for (int i = 0; i < 4; ++i) {
        #pragma unroll
        for (int j = 0; j < 2; ++j) {
            int col = col0 + wc + j * 16 + lm;
            #pragma unroll
            for (int r = 0; r < 4; ++r) {
                int row = row0 + wr + i * 16 + l4 * 4 + r;
                if (row < M) {
                    float v = acc[i][j][r];
                    if (mode == 0) {
                        if (col < NHID) xw1b[(size_t)row * NHID + col] = f2bf(v);
                        else            skipb[(size_t)row * NSKIP + (col - NHID)] = v + bias[col];
                    } else {
                        Cout[(size_t)row * NC + col] = f2bf(v);
                    }
                }
            }
        }
    }
}

// ---------------- SpMM1 + skip0(+b1+b2) + RReLU -> hb (bf16) ----------------
// one wave per node; lane covers 4 features (uint2 = 8B gather loads); 4-edge unroll
__global__ __launch_bounds__(256)
void spmm1_rrelu(const int* __restrict__ rp, const uint2* __restrict__ ep,
                 const unsigned short* __restrict__ xw1b,
                 const float* __restrict__ skipb,
                 unsigned short* __restrict__ hb, int n_nodes) {
    int n = blockIdx.x * 4 + (threadIdx.x >> 6);
    if (n >= n_nodes) return;
    int lane = threadIdx.x & 63;
    int f = lane * 4;
    int lo = rp[n], hi = rp[n + 1];
    float s0 = 0.f, s1 = 0.f, s2 = 0.f, s3 = 0.f;
    int e = lo;
    for (; e + 3 < hi; e += 4) {
        uint2 e0 = ep[e], e1 = ep[e + 1], e2 = ep[e + 2], e3 = ep[e + 3];
        uint2 p0 = *(const uint2*)(xw1b + (size_t)e0.x * NHID + f);
        uint2 p1 = *(const uint2*)(xw1b + (size_t)e1.x * NHID + f);
        uint2 p2 = *(const uint2*)(xw1b + (size_t)e2.x * NHID + f);
        uint2 p3 = *(const uint2*)(xw1b + (size_t)e3.x * NHID + f);
        float v0 = __uint_as_float(e0.y), v1 = __uint_as_float(e1.y);
        float v2 = __uint_as_float(e2.y), v3 = __uint_as_float(e3.y);
        s0 += v0 * bf_lo(p0.x) + v1 * bf_lo(p1.x) + v2 * bf_lo(p2.x) + v3 * bf_lo(p3.x);
        s1 += v0 * bf_hi(p0.x) + v1 * bf_hi(p1.x) + v2 * bf_hi(p2.x) + v3 * bf_hi(p3.x);
        s2 += v0 * bf_lo(p0.y) + v1 * bf_lo(p1.y) + v2 * bf_lo(p2.y) + v3 * bf_lo(p3.y);
        s3 += v0 * bf_hi(p0.y) + v1 * bf_hi(p1.y) + v2 * bf_hi(p2.y) + v3 * bf_hi(p3.y);
    }
    for (; e < hi; ++e) {
        uint2 ee = ep[e];
        float v = __uint_as_float(ee.y);
        uint2 p = *(const uint2*)(xw1b + (size_t)ee.x * NHID + f);
        s0 += v * bf_lo(p.x);
        s1 += v * bf_hi(p.x);
        s2 += v * bf_lo(p.y);
        s3 += v * bf_hi(p.y);
    }
    float4 sk = *(const float4*)(skipb + (size_t)n * NSKIP + f);
    float v0 = s0 + sk.x, v1 = s1 + sk.y, v2 = s2 + sk.z, v3 = s3 + sk.w;
    v0 = (v0 >= 0.f) ? v0 : v0 * RRELU_SLOPE;
    v1 = (v1 >= 0.f) ? v1 : v1 * RRELU_SLOPE;
    v2 = (v2 >= 0.f) ? v2 : v2 * RRELU_SLOPE;
    v3 = (v3 >= 0.f) ? v3 : v3 * RRELU_SLOPE;
    ushort4 o;
    o.x = f2bf(v0); o.y = f2bf(v1); o.z = f2bf(v2); o.w = f2bf(v3);
    *(ushort4*)(hb + (size_t)n * NHID + f) = o;
}

// ---------------- SpMM2 + skip1(+b3+b4) -> out ----------------
// one wave per node; lane = feature; 4-edge unroll
__global__ __launch_bounds__(256)
void spmm2_out(const int* __restrict__ rp, const uint2* __restrict__ ep,
               const unsigned short* __restrict__ hw3b,
               const float* __restrict__ skipb,
               float* __restrict__ out, int n_nodes) {
    int n = blockIdx.x * 4 + (threadIdx.x >> 6);
    if (n >= n_nodes) return;
    int f = threadIdx.x & 63;
    int lo = rp[n], hi = rp[n + 1];
    float s = 0.f;
    int e = lo;
    for (; e + 3 < hi; e += 4) {
        uint2 e0 = ep[e], e1 = ep[e + 1], e2 = ep[e + 2], e3 = ep[e + 3];
        float x0 = bf2f(hw3b[(size_t)e0.x * NCLASS + f]);
        float x1 = bf2f(hw3b[(size_t)e1.x * NCLASS + f]);
        float x2 = bf2f(hw3b[(size_t)e2.x * NCLASS + f]);
        float x3 = bf2f(hw3b[(size_t)e3.x * NCLASS + f]);
        s += __uint_as_float(e0.y) * x0 + __uint_as_float(e1.y) * x1
           + __uint_as_float(e2.y) * x2 + __uint_as_float(e3.y) * x3;
    }
    for (; e < hi; ++e) {
        uint2 ee = ep[e];
        s += __uint_as_float(ee.y) * bf2f(hw3b[(size_t)ee.x * NCLASS + f]);
    }
    out[(size_t)n * NCLASS + f] = s + skipb[(size_t)n * NSKIP + NHID + f];
}

extern "C" void kernel_launch(void* const* d_in, const int* in_sizes, int n_in,
                              void* d_out, int out_size, void* d_ws, size_t ws_size,
                              hipStream_t stream) {
    const float* x    = (const float*)d_in[0];
    const int*   erow = (const int*)d_in[1];
    const int*   ecol = (const int*)d_in[2];
    const float* ev   = (const float*)d_in[3];
    const float* w1   = (const float*)d_in[4];
    const float* b1   = (const float*)d_in[5];
    const float* w2   = (const float*)d_in[6];
    const float* b2   = (const float*)d_in[7];
    const float* w3   = (const float*)d_in[8];
    const float* b3   = (const float*)d_in[9];
    const float* w4   = (const float*)d_in[10];
    const float* b4   = (const float*)d_in[11];
    float* out = (float*)d_out;

    char* ws = (char*)d_ws;
    size_t off = 0;
    auto alloc = [&](size_t bytes) -> void* {
        off = (off + 255) & ~(size_t)255;
        void* p = ws + off;
        off += bytes;
        return p;
    };

    unsigned short* xb    = (unsigned short*)alloc((size_t)N_NODES * NFEAT * 2);
    unsigned short* Bt    = (unsigned short*)alloc((size_t)NFEAT * NCOMB * 2);
    float*          biasb = (float*)alloc(NCOMB * 4);
    unsigned short* xw1b  = (unsigned short*)alloc((size_t)N_NODES * NHID * 2);
    float*          skipb = (float*)alloc((size_t)N_NODES * NSKIP * 4);
    unsigned short* hb    = (unsigned short*)alloc((size_t)N_NODES * NHID * 2);
    unsigned short* w3t   = (unsigned short*)alloc((size_t)NHID * NCLASS * 2);
    unsigned short* hw3b  = (unsigned short*)alloc((size_t)N_NODES * NCLASS * 2);
    int*            rp    = (int*)alloc((size_t)(N_NODES + 1) * 4);
    uint2*          ep    = (uint2*)alloc((size_t)N_EDGES * 8);

    // 1) casts & packing
    cast_f32_bf16x4<<<4096, 256, 0, stream>>>(x, xb, (long)N_NODES * NFEAT / 4);
    pack_Bt<<<(NFEAT * NCOMB + 255) / 256, 256, 0, stream>>>(w1, w2, w4, b1, b2, b3, b4, Bt, biasb);
    pack_w3t<<<(NCLASS * NHID + 255) / 256, 256, 0, stream>>>(w3, w3t);
    pack_edges<<<(N_EDGES + 255) / 256, 256, 0, stream>>>(ecol, ev, ep, N_EDGES);
    build_rowptr<<<(N_NODES + 1 + 255) / 256, 256, 0, stream>>>(erow, rp, N_NODES, N_EDGES);

    // 2) fused GEMM: xb @ [w1|w2|w4] -> xw1b (bf16) | skipb (fp32, +bias)
    dim3 g1(NCOMB / GBN, (N_NODES + GBM - 1) / GBM);   // col-fastest
    gemm_bf16<<<g1, 256, 0, stream>>>(xb, Bt, biasb, nullptr, skipb, xw1b,
                                      N_NODES, NFEAT, NCOMB, 0);

    // 3) spmm(xw1) + skip0 -> rrelu -> hb (bf16)
    spmm1_rrelu<<<(N_NODES + 3) / 4, 256, 0, stream>>>(rp, ep, xw1b, skipb, hb, N_NODES);

    // 4) hw3b = hb @ w3 (bf16 out)
    dim3 g2(NCLASS / GBN, (N_NODES + GBM - 1) / GBM);
    gemm_bf16<<<g2, 256, 0, stream>>>(hb, w3t, nullptr, hw3b, nullptr, nullptr,
                                      N_NODES, NHID, NCLASS, 1);

    // 5) out = spmm(hw3) + skip1
    spmm2_out<<<(N_NODES + 3) / 4, 256, 0, stream>>>(rp, ep, hw3b, skipb, out, N_NODES);

    // 6) tuple outputs 1..4 = unchanged weights
    size_t o = (size_t)N_NODES * NCLASS;
    hipMemcpyAsync(out + o, w1, (size_t)NFEAT * NHID * 4, hipMemcpyDeviceToDevice, stream);
    o += (size_t)NFEAT * NHID;
    hipMemcpyAsync(out + o, w2, (size_t)NFEAT * NHID * 4, hipMemcpyDeviceToDevice, stream);
    o += (size_t)NFEAT * NHID;
    hipMemcpyAsync(out + o, w3, (size_t)NHID * NCLASS * 4, hipMemcpyDeviceToDevice, stream);
    o += (size_t)NHID * NCLASS;
    hipMemcpyAsync(out + o, w4, (size_t)NFEAT * NCLASS * 4, hipMemcpyDeviceToDevice, stream);
}

// Round 4
// 376.363 us; speedup vs baseline: 1.6117x; 1.0369x over previous
//
#include <hip/hip_runtime.h>

// Problem constants
#define N_NODES 50000
#define N_EDGES 800000
#define NFEAT 512
#define NHID 256
#define NCLASS 64
#define NCOMB 576
#define NSKIP 320            // NHID + NCLASS (skip0 | skip1), bf16, biases folded
#define RRELU_SLOPE 0.2291666666666667f

typedef __attribute__((ext_vector_type(8))) short bf16x8;
typedef __attribute__((ext_vector_type(4))) float f32x4;

// async global->LDS, 16B per lane; dest = wave-uniform base + lane*16
#define GLOAD_LDS16(g, l)                                                      \
    __builtin_amdgcn_global_load_lds(                                          \
        (const __attribute__((address_space(1))) void*)(g),                    \
        (__attribute__((address_space(3))) void*)(l), 16, 0, 0)

__device__ __forceinline__ unsigned short f2bf(float f) {
    unsigned int x = __float_as_uint(f);
    unsigned int r = (x + 0x7fffu + ((x >> 16) & 1u)) >> 16;
    return (unsigned short)r;
}
__device__ __forceinline__ float bf2f(unsigned short u) {
    return __uint_as_float(((unsigned int)u) << 16);
}
__device__ __forceinline__ float bf_lo(unsigned int u) { return __uint_as_float(u << 16); }
__device__ __forceinline__ float bf_hi(unsigned int u) { return __uint_as_float(u & 0xffff0000u); }

// ---------------- cast fp32 -> bf16, 4 elems/thread ----------------
__global__ void cast_f32_bf16x4(const float* __restrict__ in,
                                unsigned short* __restrict__ out, long n4) {
    long i = (long)blockIdx.x * blockDim.x + threadIdx.x;
    long stride = (long)gridDim.x * blockDim.x;
    for (; i < n4; i += stride) {
        float4 v = ((const float4*)in)[i];
        ushort4 o;
        o.x = f2bf(v.x); o.y = f2bf(v.y); o.z = f2bf(v.z); o.w = f2bf(v.w);
        ((ushort4*)out)[i] = o;
    }
}

// -------- pack Bt = [w1|w2|w4]^T as [NCOMB, NFEAT] bf16; bias (b1+b2 | b3+b4 folded)
__global__ void pack_Bt(const float* __restrict__ w1, const float* __restrict__ w2,
                        const float* __restrict__ w4, const float* __restrict__ b1,
                        const float* __restrict__ b2, const float* __restrict__ b3,
                        const float* __restrict__ b4,
                        unsigned short* __restrict__ Bt, float* __restrict__ biasb) {
    int i = blockIdx.x * blockDim.x + threadIdx.x;
    const int total = NFEAT * NCOMB;
    if (i < total) {
        int c = i >> 9;            // NFEAT=512
        int k = i & 511;
        float v;
        if (c < NHID)            v = w1[k * NHID + c];
        else if (c < 2 * NHID)   v = w2[k * NHID + (c - NHID)];
        else                     v = w4[k * NCLASS + (c - 2 * NHID)];
        Bt[i] = f2bf(v);
    }
    if (i < NCOMB) {
        float b = 0.f;
        if (i >= NHID && i < 2 * NHID) b = b1[i - NHID] + b2[i - NHID];
        else if (i >= 2 * NHID)        b = b3[i - 2 * NHID] + b4[i - 2 * NHID];
        biasb[i] = b;
    }
}

// ---------------- pack w3t [NCLASS, NHID] bf16 ----------------
__global__ void pack_w3t(const float* __restrict__ w3, unsigned short* __restrict__ w3t) {
    int i = blockIdx.x * blockDim.x + threadIdx.x;
    if (i < NCLASS * NHID) {
        int c = i >> 8;            // NHID=256
        int k = i & 255;
        w3t[i] = f2bf(w3[k * NCLASS + c]);
    }
}

// ---------------- pack edges: (col, val_bits) ----------------
__global__ void pack_edges(const int* __restrict__ ecol, const float* __restrict__ ev,
                           uint2* __restrict__ ep, int n) {
    int i = blockIdx.x * blockDim.x + threadIdx.x;
    if (i < n) {
        uint2 e;
        e.x = (unsigned)ecol[i];
        e.y = __float_as_uint(ev[i]);
        ep[i] = e;
    }
}

// ---------------- row_ptr from sorted COO rows ----------------
__global__ void build_rowptr(const int* __restrict__ erow, int* __restrict__ rp,
                             int n_nodes, int n_edges) {
    int n = blockIdx.x * blockDim.x + threadIdx.x;
    if (n > n_nodes) return;
    int lo = 0, hi = n_edges;
    while (lo < hi) {
        int mid = (lo + hi) >> 1;
        if (erow[mid] < n) lo = mid + 1; else hi = mid;
    }
    rp[n] = lo;
}

// ---------------- bf16 MFMA GEMM (templated col-tile) ----------------
// Tile 128 x BN, BK=64. global_load_lds(16B) staging, XOR-octet swizzle (no pad).
// LDS row = 64 bf16 = 128 B = 8 octets of 16 B; octet g of row r stored at slot g^(r&7).
// grid: x = col-block (fastest -> A-panel locality), y = row-panel.
// MODE 0 (BN=192): cols<256 -> xw1b bf16; cols>=256 -> skipb bf16 (+bias)
// MODE 1 (BN=64):  bf16 output to Cout [M, NC]
#define GBM 128
#define GBK 64

template <int BN, int MODE>
__global__ __launch_bounds__(256)
void gemm_bf16(const unsigned short* __restrict__ A,   // [M,K] bf16 row-major
               const unsigned short* __restrict__ Bt,  // [NC,K] bf16 row-major (B^T)
               const float* __restrict__ bias,
               unsigned short* __restrict__ Cout,
               unsigned short* __restrict__ skipb,
               unsigned short* __restrict__ xw1b,
               int M, int K, int NC) {
    constexpr int CF = BN / 32;               // col-frags per wave (6 or 2)
    __shared__ unsigned short As[GBM * GBK];  // 16 KB
    __shared__ unsigned short Bs[BN * GBK];   // 24 KB (BN=192) / 8 KB (BN=64)
    const int tid  = threadIdx.x;
    const int lane = tid & 63;
    const int wave = tid >> 6;
    const int col0 = blockIdx.x * BN;
    const int row0 = blockIdx.y * GBM;
    const int wr = (wave >> 1) * 64;
    const int wc = (wave & 1) * (BN / 2);
    const int lm = lane & 15;
    const int l4 = lane >> 4;       // 0..3 (k-octet within 32-k chunk)
    const int sw = lm & 7;          // row-based swizzle key for frag reads

    // staging lane decomposition: 1024 B per wave-issue = 8 rows x 8 octets
    const int sub  = lane >> 3;     // row within 8-row chunk
    const int slot = lane & 7;      // LDS octet slot this lane fills
    const int goct = slot ^ sub;    // global octet to fetch for that slot

    f32x4 acc[4][CF] = {};

    for (int k0 = 0; k0 < K; k0 += GBK) {
        // stage A: 16 chunks of 8 rows; 4 per wave
        #pragma unroll
        for (int p = 0; p < 4; ++p) {
            int chunk = wave * 4 + p;
            int gr = row0 + chunk * 8 + sub;
            if (gr > M - 1) gr = M - 1;     // clamp (dup rows only feed unsaved acc)
            GLOAD_LDS16(A + (size_t)gr * K + k0 + goct * 8, As + chunk * 512);
        }
        // stage B: BN/8 chunks of 8 rows; BN/32 per wave
        #pragma unroll
        for (int p = 0; p < BN / 32; ++p) {
            int chunk = wave * (BN / 32) + p;
            int rb = col0 + chunk * 8 + sub;
            GLOAD_LDS16(Bt + (size_t)rb * K + k0 + goct * 8, Bs + chunk * 512);
        }
        __syncthreads();

        #pragma unroll
        for (int kk8 = 0; kk8 < GBK / 8; kk8 += 4) {   // two 32-k steps
            const int so = ((kk8 + l4) ^ sw) * 8;
            bf16x8 bfr[CF];
            #pragma unroll
            for (int j = 0; j < CF; ++j)
                bfr[j] = *(const bf16x8*)(Bs + (wc + j * 16 + lm) * 64 + so);
            #pragma unroll
            for (int i = 0; i < 4; ++i) {
                bf16x8 af = *(const bf16x8*)(As + (wr + i * 16 + lm) * 64 + so);
                #pragma unroll
                for (int j = 0; j < CF; ++j)
                    acc[i][j] = __builtin_amdgcn_mfma_f32_16x16x32_bf16(af, bfr[j], acc[i][j], 0, 0, 0);
            }
        }
        __syncthreads();
    }

    // epilogue: C/D layout col=lane&15, row=(lane>>4)*4+reg
    #pragma unroll
    for (int i = 0; i < 4; ++i) {
        #pragma unroll
        for (int j = 0; j < CF; ++j) {
            int col = col0 + wc + j * 16 + lm;
            float bvv = (MODE == 0) ? bias[col] : 0.f;
            #pragma unroll
            for (int r = 0; r < 4; ++r) {
                int row = row0 + wr + i * 16 + l4 * 4 + r;
                if (row < M) {
                    float v = acc[i][j][r];
                    if (MODE == 0) {
                        if (col < NHID) xw1b[(size_t)row * NHID + col] = f2bf(v);
                        else            skipb[(size_t)row * NSKIP + (col - NHID)] = f2bf(v + bvv);
                    } else {
                        Cout[(size_t)row * NC + col] = f2bf(v);
                    }
                }
            }
        }
    }
}

// ---------------- SpMM1 + skip0(+b1+b2) + RReLU -> hb (bf16) ----------------
// one wave per node; lane covers 4 features (uint2 = 8B gather loads); 4-edge unroll
__global__ __launch_bounds__(256)
void spmm1_rrelu(const int* __restrict__ rp, const uint2* __restrict__ ep,
                 const unsigned short* __restrict__ xw1b,
                 const unsigned short* __restrict__ skipb,
                 unsigned short* __restrict__ hb, int n_nodes) {
    int n = blockIdx.x * 4 + (threadIdx.x >> 6);
    if (n >= n_nodes) return;
    int lane = threadIdx.x & 63;
    int f = lane * 4;
    int lo = rp[n], hi = rp[n + 1];
    float s0 = 0.f, s1 = 0.f, s2 = 0.f, s3 = 0.f;
    int e = lo;
    for (; e + 3 < hi; e += 4) {
        uint2 e0 = ep[e], e1 = ep[e + 1], e2 = ep[e + 2], e3 = ep[e + 3];
        uint2 p0 = *(const uint2*)(xw1b + (size_t)e0.x * NHID + f);
        uint2 p1 = *(const uint2*)(xw1b + (size_t)e1.x * NHID + f);
        uint2 p2 = *(const uint2*)(xw1b + (size_t)e2.x * NHID + f);
        uint2 p3 = *(const uint2*)(xw1b + (size_t)e3.x * NHID + f);
        float v0 = __uint_as_float(e0.y), v1 = __uint_as_float(e1.y);
        float v2 = __uint_as_float(e2.y), v3 = __uint_as_float(e3.y);
        s0 += v0 * bf_lo(p0.x) + v1 * bf_lo(p1.x) + v2 * bf_lo(p2.x) + v3 * bf_lo(p3.x);
        s1 += v0 * bf_hi(p0.x) + v1 * bf_hi(p1.x) + v2 * bf_hi(p2.x) + v3 * bf_hi(p3.x);
        s2 += v0 * bf_lo(p0.y) + v1 * bf_lo(p1.y) + v2 * bf_lo(p2.y) + v3 * bf_lo(p3.y);
        s3 += v0 * bf_hi(p0.y) + v1 * bf_hi(p1.y) + v2 * bf_hi(p2.y) + v3 * bf_hi(p3.y);
    }
    for (; e < hi; ++e) {
        uint2 ee = ep[e];
        float v = __uint_as_float(ee.y);
        uint2 p = *(const uint2*)(xw1b + (size_t)ee.x * NHID + f);
        s0 += v * bf_lo(p.x);
        s1 += v * bf_hi(p.x);
        s2 += v * bf_lo(p.y);
        s3 += v * bf_hi(p.y);
    }
    ushort4 sk = *(const ushort4*)(skipb + (size_t)n * NSKIP + f);
    float v0 = s0 + bf2f(sk.x), v1 = s1 + bf2f(sk.y);
    float v2 = s2 + bf2f(sk.z), v3 = s3 + bf2f(sk.w);
    v0 = (v0 >= 0.f) ? v0 : v0 * RRELU_SLOPE;
    v1 = (v1 >= 0.f) ? v1 : v1 * RRELU_SLOPE;
    v2 = (v2 >= 0.f) ? v2 : v2 * RRELU_SLOPE;
    v3 = (v3 >= 0.f) ? v3 : v3 * RRELU_SLOPE;
    ushort4 o;
    o.x = f2bf(v0); o.y = f2bf(v1); o.z = f2bf(v2); o.w = f2bf(v3);
    *(ushort4*)(hb + (size_t)n * NHID + f) = o;
}

// ---------------- SpMM2 + skip1(+b3+b4) -> out ----------------
// one wave per node; lane = feature; 4-edge unroll
__global__ __launch_bounds__(256)
void spmm2_out(const int* __restrict__ rp, const uint2* __restrict__ ep,
               const unsigned short* __restrict__ hw3b,
               const unsigned short* __restrict__ skipb,
               float* __restrict__ out, int n_nodes) {
    int n = blockIdx.x * 4 + (threadIdx.x >> 6);
    if (n >= n_nodes) return;
    int f = threadIdx.x & 63;
    int lo = rp[n], hi = rp[n + 1];
    float s = 0.f;
    int e = lo;
    for (; e + 3 < hi; e += 4) {
        uint2 e0 = ep[e], e1 = ep[e + 1], e2 = ep[e + 2], e3 = ep[e + 3];
        float x0 = bf2f(hw3b[(size_t)e0.x * NCLASS + f]);
        float x1 = bf2f(hw3b[(size_t)e1.x * NCLASS + f]);
        float x2 = bf2f(hw3b[(size_t)e2.x * NCLASS + f]);
        float x3 = bf2f(hw3b[(size_t)e3.x * NCLASS + f]);
        s += __uint_as_float(e0.y) * x0 + __uint_as_float(e1.y) * x1
           + __uint_as_float(e2.y) * x2 + __uint_as_float(e3.y) * x3;
    }
    for (; e < hi; ++e) {
        uint2 ee = ep[e];
        s += __uint_as_float(ee.y) * bf2f(hw3b[(size_t)ee.x * NCLASS + f]);
    }
    out[(size_t)n * NCLASS + f] = s + bf2f(skipb[(size_t)n * NSKIP + NHID + f]);
}

extern "C" void kernel_launch(void* const* d_in, const int* in_sizes, int n_in,
                              void* d_out, int out_size, void* d_ws, size_t ws_size,
                              hipStream_t stream) {
    const float* x    = (const float*)d_in[0];
    const int*   erow = (const int*)d_in[1];
    const int*   ecol = (const int*)d_in[2];
    const float* ev   = (const float*)d_in[3];
    const float* w1   = (const float*)d_in[4];
    const float* b1   = (const float*)d_in[5];
    const float* w2   = (const float*)d_in[6];
    const float* b2   = (const float*)d_in[7];
    const float* w3   = (const float*)d_in[8];
    const float* b3   = (const float*)d_in[9];
    const float* w4   = (const float*)d_in[10];
    const float* b4   = (const float*)d_in[11];
    float* out = (float*)d_out;

    char* ws = (char*)d_ws;
    size_t off = 0;
    auto alloc = [&](size_t bytes) -> void* {
        off = (off + 255) & ~(size_t)255;
        void* p = ws + off;
        off += bytes;
        return p;
    };

    unsigned short* xb    = (unsigned short*)alloc((size_t)N_NODES * NFEAT * 2);
    unsigned short* Bt    = (unsigned short*)alloc((size_t)NFEAT * NCOMB * 2);
    float*          biasb = (float*)alloc(NCOMB * 4);
    unsigned short* xw1b  = (unsigned short*)alloc((size_t)N_NODES * NHID * 2);
    unsigned short* skipb = (unsigned short*)alloc((size_t)N_NODES * NSKIP * 2);
    unsigned short* hb    = (unsigned short*)alloc((size_t)N_NODES * NHID * 2);
    unsigned short* w3t   = (unsigned short*)alloc((size_t)NHID * NCLASS * 2);
    unsigned short* hw3b  = (unsigned short*)alloc((size_t)N_NODES * NCLASS * 2);
    int*            rp    = (int*)alloc((size_t)(N_NODES + 1) * 4);
    uint2*          ep    = (uint2*)alloc((size_t)N_EDGES * 8);

    // 1) casts & packing
    cast_f32_bf16x4<<<4096, 256, 0, stream>>>(x, xb, (long)N_NODES * NFEAT / 4);
    pack_Bt<<<(NFEAT * NCOMB + 255) / 256, 256, 0, stream>>>(w1, w2, w4, b1, b2, b3, b4, Bt, biasb);
    pack_w3t<<<(NCLASS * NHID + 255) / 256, 256, 0, stream>>>(w3, w3t);
    pack_edges<<<(N_EDGES + 255) / 256, 256, 0, stream>>>(ecol, ev, ep, N_EDGES);
    build_rowptr<<<(N_NODES + 1 + 255) / 256, 256, 0, stream>>>(erow, rp, N_NODES, N_EDGES);

    // 2) fused GEMM: xb @ [w1|w2|w4] -> xw1b (bf16) | skipb (bf16, +bias)
    dim3 g1(NCOMB / 192, (N_NODES + GBM - 1) / GBM);   // col-fastest, 3 col-blocks
    gemm_bf16<192, 0><<<g1, 256, 0, stream>>>(xb, Bt, biasb, nullptr, skipb, xw1b,
                                              N_NODES, NFEAT, NCOMB);

    // 3) spmm(xw1) + skip0 -> rrelu -> hb (bf16)
    spmm1_rrelu<<<(N_NODES + 3) / 4, 256, 0, stream>>>(rp, ep, xw1b, skipb, hb, N_NODES);

    // 4) hw3b = hb @ w3 (bf16 out)
    dim3 g2(NCLASS / 64, (N_NODES + GBM - 1) / GBM);
    gemm_bf16<64, 1><<<g2, 256, 0, stream>>>(hb, w3t, nullptr, hw3b, nullptr, nullptr,
                                             N_NODES, NHID, NCLASS);

    // 5) out = spmm(hw3) + skip1
    spmm2_out<<<(N_NODES + 3) / 4, 256, 0, stream>>>(rp, ep, hw3b, skipb, out, N_NODES);

    // 6) tuple outputs 1..4 = unchanged weights
    size_t o = (size_t)N_NODES * NCLASS;
    hipMemcpyAsync(out + o, w1, (size_t)NFEAT * NHID * 4, hipMemcpyDeviceToDevice, stream);
    o += (size_t)NFEAT * NHID;
    hipMemcpyAsync(out + o, w2, (size_t)NFEAT * NHID * 4, hipMemcpyDeviceToDevice, stream);
    o += (size_t)NFEAT * NHID;
    hipMemcpyAsync(out + o, w3, (size_t)NHID * NCLASS * 4, hipMemcpyDeviceToDevice, stream);
    o += (size_t)NHID * NCLASS;
    hipMemcpyAsync(out + o, w4, (size_t)NFEAT * NCLASS * 4, hipMemcpyDeviceToDevice, stream);
}

// Round 5
// 353.824 us; speedup vs baseline: 1.7143x; 1.0637x over previous
//
#include <hip/hip_runtime.h>

// Problem constants
#define N_NODES 50000
#define N_EDGES 800000
#define NFEAT 512
#define NHID 256
#define NCLASS 64
#define NCOMB 576
#define NSKIP 320            // NHID + NCLASS (skip0 | skip1), bf16, biases folded
#define RRELU_SLOPE 0.2291666666666667f

typedef __attribute__((ext_vector_type(8))) short bf16x8;
typedef __attribute__((ext_vector_type(4))) float f32x4;

// async global->LDS, 16B per lane; dest = wave-uniform base + lane*16
#define GLOAD_LDS16(g, l)                                                      \
    __builtin_amdgcn_global_load_lds(                                          \
        (const __attribute__((address_space(1))) void*)(g),                    \
        (__attribute__((address_space(3))) void*)(l), 16, 0, 0)

__device__ __forceinline__ unsigned short f2bf(float f) {
    unsigned int x = __float_as_uint(f);
    unsigned int r = (x + 0x7fffu + ((x >> 16) & 1u)) >> 16;
    return (unsigned short)r;
}
__device__ __forceinline__ float bf2f(unsigned short u) {
    return __uint_as_float(((unsigned int)u) << 16);
}
__device__ __forceinline__ float bf_lo(unsigned int u) { return __uint_as_float(u << 16); }
__device__ __forceinline__ float bf_hi(unsigned int u) { return __uint_as_float(u & 0xffff0000u); }

// ---------------- cast fp32 -> bf16, 4 elems/thread ----------------
__global__ void cast_f32_bf16x4(const float* __restrict__ in,
                                unsigned short* __restrict__ out, long n4) {
    long i = (long)blockIdx.x * blockDim.x + threadIdx.x;
    long stride = (long)gridDim.x * blockDim.x;
    for (; i < n4; i += stride) {
        float4 v = ((const float4*)in)[i];
        ushort4 o;
        o.x = f2bf(v.x); o.y = f2bf(v.y); o.z = f2bf(v.z); o.w = f2bf(v.w);
        ((ushort4*)out)[i] = o;
    }
}

// -------- pack Bt = [w1|w2|w4]^T as [NCOMB, NFEAT] bf16; bias (b1+b2 | b3+b4 folded)
__global__ void pack_Bt(const float* __restrict__ w1, const float* __restrict__ w2,
                        const float* __restrict__ w4, const float* __restrict__ b1,
                        const float* __restrict__ b2, const float* __restrict__ b3,
                        const float* __restrict__ b4,
                        unsigned short* __restrict__ Bt, float* __restrict__ biasb) {
    int i = blockIdx.x * blockDim.x + threadIdx.x;
    const int total = NFEAT * NCOMB;
    if (i < total) {
        int c = i >> 9;            // NFEAT=512
        int k = i & 511;
        float v;
        if (c < NHID)            v = w1[k * NHID + c];
        else if (c < 2 * NHID)   v = w2[k * NHID + (c - NHID)];
        else                     v = w4[k * NCLASS + (c - 2 * NHID)];
        Bt[i] = f2bf(v);
    }
    if (i < NCOMB) {
        float b = 0.f;
        if (i >= NHID && i < 2 * NHID) b = b1[i - NHID] + b2[i - NHID];
        else if (i >= 2 * NHID)        b = b3[i - 2 * NHID] + b4[i - 2 * NHID];
        biasb[i] = b;
    }
}

// ---------------- pack w3t [NCLASS, NHID] bf16 ----------------
__global__ void pack_w3t(const float* __restrict__ w3, unsigned short* __restrict__ w3t) {
    int i = blockIdx.x * blockDim.x + threadIdx.x;
    if (i < NCLASS * NHID) {
        int c = i >> 8;            // NHID=256
        int k = i & 255;
        w3t[i] = f2bf(w3[k * NCLASS + c]);
    }
}

// ---------------- pack edges: (col, val_bits) ----------------
__global__ void pack_edges(const int* __restrict__ ecol, const float* __restrict__ ev,
                           uint2* __restrict__ ep, int n) {
    int i = blockIdx.x * blockDim.x + threadIdx.x;
    if (i < n) {
        uint2 e;
        e.x = (unsigned)ecol[i];
        e.y = __float_as_uint(ev[i]);
        ep[i] = e;
    }
}

// ---------------- row_ptr from sorted COO rows ----------------
__global__ void build_rowptr(const int* __restrict__ erow, int* __restrict__ rp,
                             int n_nodes, int n_edges) {
    int n = blockIdx.x * blockDim.x + threadIdx.x;
    if (n > n_nodes) return;
    int lo = 0, hi = n_edges;
    while (lo < hi) {
        int mid = (lo + hi) >> 1;
        if (erow[mid] < n) lo = mid + 1; else hi = mid;
    }
    rp[n] = lo;
}

// ---------------- bf16 MFMA GEMM (templated col-tile) ----------------
// Tile 128 x BN, BK=64. global_load_lds(16B) staging, XOR-octet swizzle (no pad).
// LDS row = 64 bf16 = 128 B = 8 octets of 16 B; octet g of row r stored at slot g^(r&7).
// MODE 0 (BN=96): 1D grid, XCD-co-schedule swizzle — the NCB col-blocks of one
//   row-panel get ids == same (mod 8) so they land on one XCD and share its L2
//   copy of the 131KB A-panel. cols<256 -> xw1b bf16; cols>=256 -> skipb bf16 (+bias)
// MODE 1 (BN=64): 2D grid; bf16 output to Cout [M, NC]
#define GBM 128
#define GBK 64
#define NCB0 6               // NCOMB / 96 col-blocks in mode 0
#define NRP0 392             // row-panels in mode 0, padded to multiple of 8

template <int BN, int MODE>
__global__ __launch_bounds__(256)
void gemm_bf16(const unsigned short* __restrict__ A,   // [M,K] bf16 row-major
               const unsigned short* __restrict__ Bt,  // [NC,K] bf16 row-major (B^T)
               const float* __restrict__ bias,
               unsigned short* __restrict__ Cout,
               unsigned short* __restrict__ skipb,
               unsigned short* __restrict__ xw1b,
               int M, int K, int NC) {
    constexpr int CF = BN / 32;               // col-frags per wave (3 or 2)
    __shared__ unsigned short As[GBM * GBK];  // 16 KB
    __shared__ unsigned short Bs[BN * GBK];   // 12 KB (96) / 8 KB (64)
    int row0, col0;
    if (MODE == 0) {
        // group of 8*NCB0 consecutive ids = 8 row-panels x NCB0 cols;
        // within group, id%8 = row-panel (=XCD), id/8 = col-block.
        int b = blockIdx.x;
        int g = b / (8 * NCB0);
        int w = b % (8 * NCB0);
        int r = g * 8 + (w & 7);
        int c = w >> 3;
        if (r * GBM >= M) return;           // padded tail
        row0 = r * GBM;
        col0 = c * BN;
    } else {
        col0 = blockIdx.x * BN;
        row0 = blockIdx.y * GBM;
    }
    const int tid  = threadIdx.x;
    const int lane = tid & 63;
    const int wave = tid >> 6;
    const int wr = (wave >> 1) * 64;
    const int wc = (wave & 1) * (BN / 2);
    const int lm = lane & 15;
    const int l4 = lane >> 4;       // 0..3 (k-octet within 32-k chunk)
    const int sw = lm & 7;          // row-based swizzle key for frag reads

    // staging lane decomposition: 1024 B per wave-issue = 8 rows x 8 octets
    const int sub  = lane >> 3;     // row within 8-row chunk
    const int slot = lane & 7;      // LDS octet slot this lane fills
    const int goct = slot ^ sub;    // global octet to fetch for that slot

    f32x4 acc[4][CF] = {};

    for (int k0 = 0; k0 < K; k0 += GBK) {
        // stage A: 16 chunks of 8 rows; 4 per wave
        #pragma unroll
        for (int p = 0; p < 4; ++p) {
            int chunk = wave * 4 + p;
            int gr = row0 + chunk * 8 + sub;
            if (gr > M - 1) gr = M - 1;     // clamp (dup rows only feed unsaved acc)
            GLOAD_LDS16(A + (size_t)gr * K + k0 + goct * 8, As + chunk * 512);
        }
        // stage B: BN/8 chunks of 8 rows; BN/32 per wave
        #pragma unroll
        for (int p = 0; p < BN / 32; ++p) {
            int chunk = wave * (BN / 32) + p;
            int rb = col0 + chunk * 8 + sub;
            GLOAD_LDS16(Bt + (size_t)rb * K + k0 + goct * 8, Bs + chunk * 512);
        }
        __syncthreads();

        #pragma unroll
        for (int kk8 = 0; kk8 < GBK / 8; kk8 += 4) {   // two 32-k steps
            const int so = ((kk8 + l4) ^ sw) * 8;
            bf16x8 bfr[CF];
            #pragma unroll
            for (int j = 0; j < CF; ++j)
                bfr[j] = *(const bf16x8*)(Bs + (wc + j * 16 + lm) * 64 + so);
            #pragma unroll
            for (int i = 0; i < 4; ++i) {
                bf16x8 af = *(const bf16x8*)(As + (wr + i * 16 + lm) * 64 + so);
                #pragma unroll
                for (int j = 0; j < CF; ++j)
                    acc[i][j] = __builtin_amdgcn_mfma_f32_16x16x32_bf16(af, bfr[j], acc[i][j], 0, 0, 0);
            }
        }
        __syncthreads();
    }

    // epilogue: C/D layout col=lane&15, row=(lane>>4)*4+reg
    #pragma unroll
    for (int i = 0; i < 4; ++i) {
        #pragma unroll
        for (int j = 0; j < CF; ++j) {
            int col = col0 + wc + j * 16 + lm;
            float bvv = (MODE == 0) ? bias[col] : 0.f;
            #pragma unroll
            for (int r = 0; r < 4; ++r) {
                int row = row0 + wr + i * 16 + l4 * 4 + r;
                if (row < M) {
                    float v = acc[i][j][r];
                    if (MODE == 0) {
                        if (col < NHID) xw1b[(size_t)row * NHID + col] = f2bf(v);
                        else            skipb[(size_t)row * NSKIP + (col - NHID)] = f2bf(v + bvv);
                    } else {
                        Cout[(size_t)row * NC + col] = f2bf(v);
                    }
                }
            }
        }
    }
}

// ---------------- SpMM1 + skip0(+b1+b2) + RReLU -> hb (bf16) ----------------
// one wave per node; lane covers 4 features (uint2 = 8B gather loads); 8-edge unroll
__global__ __launch_bounds__(256)
void spmm1_rrelu(const int* __restrict__ rp, const uint2* __restrict__ ep,
                 const unsigned short* __restrict__ xw1b,
                 const unsigned short* __restrict__ skipb,
                 unsigned short* __restrict__ hb, int n_nodes) {
    int n = blockIdx.x * 4 + (threadIdx.x >> 6);
    if (n >= n_nodes) return;
    int lane = threadIdx.x & 63;
    int f = lane * 4;
    int lo = rp[n], hi = rp[n + 1];
    float s0 = 0.f, s1 = 0.f, s2 = 0.f, s3 = 0.f;
    int e = lo;
    for (; e + 7 < hi; e += 8) {
        uint2 ed[8], p[8];
        #pragma unroll
        for (int q = 0; q < 8; ++q) ed[q] = ep[e + q];
        #pragma unroll
        for (int q = 0; q < 8; ++q)
            p[q] = *(const uint2*)(xw1b + (size_t)ed[q].x * NHID + f);
        #pragma unroll
        for (int q = 0; q < 8; ++q) {
            float v = __uint_as_float(ed[q].y);
            s0 += v * bf_lo(p[q].x);
            s1 += v * bf_hi(p[q].x);
            s2 += v * bf_lo(p[q].y);
            s3 += v * bf_hi(p[q].y);
        }
    }
    for (; e < hi; ++e) {
        uint2 ee = ep[e];
        float v = __uint_as_float(ee.y);
        uint2 p = *(const uint2*)(xw1b + (size_t)ee.x * NHID + f);
        s0 += v * bf_lo(p.x);
        s1 += v * bf_hi(p.x);
        s2 += v * bf_lo(p.y);
        s3 += v * bf_hi(p.y);
    }
    ushort4 sk = *(const ushort4*)(skipb + (size_t)n * NSKIP + f);
    float v0 = s0 + bf2f(sk.x), v1 = s1 + bf2f(sk.y);
    float v2 = s2 + bf2f(sk.z), v3 = s3 + bf2f(sk.w);
    v0 = (v0 >= 0.f) ? v0 : v0 * RRELU_SLOPE;
    v1 = (v1 >= 0.f) ? v1 : v1 * RRELU_SLOPE;
    v2 = (v2 >= 0.f) ? v2 : v2 * RRELU_SLOPE;
    v3 = (v3 >= 0.f) ? v3 : v3 * RRELU_SLOPE;
    ushort4 o;
    o.x = f2bf(v0); o.y = f2bf(v1); o.z = f2bf(v2); o.w = f2bf(v3);
    *(ushort4*)(hb + (size_t)n * NHID + f) = o;
}

// ---------------- SpMM2 + skip1(+b3+b4) -> out ----------------
// one wave per node; lane = feature; 8-edge unroll
__global__ __launch_bounds__(256)
void spmm2_out(const int* __restrict__ rp, const uint2* __restrict__ ep,
               const unsigned short* __restrict__ hw3b,
               const unsigned short* __restrict__ skipb,
               float* __restrict__ out, int n_nodes) {
    int n = blockIdx.x * 4 + (threadIdx.x >> 6);
    if (n >= n_nodes) return;
    int f = threadIdx.x & 63;
    int lo = rp[n], hi = rp[n + 1];
    float s = 0.f;
    int e = lo;
    for (; e + 7 < hi; e += 8) {
        uint2 ed[8];
        unsigned short h[8];
        #pragma unroll
        for (int q = 0; q < 8; ++q) ed[q] = ep[e + q];
        #pragma unroll
        for (int q = 0; q < 8; ++q) h[q] = hw3b[(size_t)ed[q].x * NCLASS + f];
        #pragma unroll
        for (int q = 0; q < 8; ++q)
            s += __uint_as_float(ed[q].y) * bf2f(h[q]);
    }
    for (; e < hi; ++e) {
        uint2 ee = ep[e];
        s += __uint_as_float(ee.y) * bf2f(hw3b[(size_t)ee.x * NCLASS + f]);
    }
    out[(size_t)n * NCLASS + f] = s + bf2f(skipb[(size_t)n * NSKIP + NHID + f]);
}

extern "C" void kernel_launch(void* const* d_in, const int* in_sizes, int n_in,
                              void* d_out, int out_size, void* d_ws, size_t ws_size,
                              hipStream_t stream) {
    const float* x    = (const float*)d_in[0];
    const int*   erow = (const int*)d_in[1];
    const int*   ecol = (const int*)d_in[2];
    const float* ev   = (const float*)d_in[3];
    const float* w1   = (const float*)d_in[4];
    const float* b1   = (const float*)d_in[5];
    const float* w2   = (const float*)d_in[6];
    const float* b2   = (const float*)d_in[7];
    const float* w3   = (const float*)d_in[8];
    const float* b3   = (const float*)d_in[9];
    const float* w4   = (const float*)d_in[10];
    const float* b4   = (const float*)d_in[11];
    float* out = (float*)d_out;

    char* ws = (char*)d_ws;
    size_t off = 0;
    auto alloc = [&](size_t bytes) -> void* {
        off = (off + 255) & ~(size_t)255;
        void* p = ws + off;
        off += bytes;
        return p;
    };

    unsigned short* xb    = (unsigned short*)alloc((size_t)N_NODES * NFEAT * 2);
    unsigned short* Bt    = (unsigned short*)alloc((size_t)NFEAT * NCOMB * 2);
    float*          biasb = (float*)alloc(NCOMB * 4);
    unsigned short* xw1b  = (unsigned short*)alloc((size_t)N_NODES * NHID * 2);
    unsigned short* skipb = (unsigned short*)alloc((size_t)N_NODES * NSKIP * 2);
    unsigned short* hb    = (unsigned short*)alloc((size_t)N_NODES * NHID * 2);
    unsigned short* w3t   = (unsigned short*)alloc((size_t)NHID * NCLASS * 2);
    unsigned short* hw3b  = (unsigned short*)alloc((size_t)N_NODES * NCLASS * 2);
    int*            rp    = (int*)alloc((size_t)(N_NODES + 1) * 4);
    uint2*          ep    = (uint2*)alloc((size_t)N_EDGES * 8);

    // 1) casts & packing
    cast_f32_bf16x4<<<4096, 256, 0, stream>>>(x, xb, (long)N_NODES * NFEAT / 4);
    pack_Bt<<<(NFEAT * NCOMB + 255) / 256, 256, 0, stream>>>(w1, w2, w4, b1, b2, b3, b4, Bt, biasb);
    pack_w3t<<<(NCLASS * NHID + 255) / 256, 256, 0, stream>>>(w3, w3t);
    pack_edges<<<(N_EDGES + 255) / 256, 256, 0, stream>>>(ecol, ev, ep, N_EDGES);
    build_rowptr<<<(N_NODES + 1 + 255) / 256, 256, 0, stream>>>(erow, rp, N_NODES, N_EDGES);

    // 2) fused GEMM: xb @ [w1|w2|w4] -> xw1b (bf16) | skipb (bf16, +bias)
    //    1D swizzled grid: 392 row-panels (padded) x 6 col-blocks
    gemm_bf16<96, 0><<<NRP0 * NCB0, 256, 0, stream>>>(xb, Bt, biasb, nullptr, skipb, xw1b,
                                                      N_NODES, NFEAT, NCOMB);

    // 3) spmm(xw1) + skip0 -> rrelu -> hb (bf16)
    spmm1_rrelu<<<(N_NODES + 3) / 4, 256, 0, stream>>>(rp, ep, xw1b, skipb, hb, N_NODES);

    // 4) hw3b = hb @ w3 (bf16 out)
    dim3 g2(NCLASS / 64, (N_NODES + GBM - 1) / GBM);
    gemm_bf16<64, 1><<<g2, 256, 0, stream>>>(hb, w3t, nullptr, hw3b, nullptr, nullptr,
                                             N_NODES, NHID, NCLASS);

    // 5) out = spmm(hw3) + skip1
    spmm2_out<<<(N_NODES + 3) / 4, 256, 0, stream>>>(rp, ep, hw3b, skipb, out, N_NODES);

    // 6) tuple outputs 1..4 = unchanged weights
    size_t o = (size_t)N_NODES * NCLASS;
    hipMemcpyAsync(out + o, w1, (size_t)NFEAT * NHID * 4, hipMemcpyDeviceToDevice, stream);
    o += (size_t)NFEAT * NHID;
    hipMemcpyAsync(out + o, w2, (size_t)NFEAT * NHID * 4, hipMemcpyDeviceToDevice, stream);
    o += (size_t)NFEAT * NHID;
    hipMemcpyAsync(out + o, w3, (size_t)NHID * NCLASS * 4, hipMemcpyDeviceToDevice, stream);
    o += (size_t)NHID * NCLASS;
    hipMemcpyAsync(out + o, w4, (size_t)NFEAT * NCLASS * 4, hipMemcpyDeviceToDevice, stream);
}

// Round 6
// 339.956 us; speedup vs baseline: 1.7843x; 1.0408x over previous
//
#include <hip/hip_runtime.h>

// Problem constants
#define N_NODES 50000
#define N_EDGES 800000
#define NFEAT 512
#define NHID 256
#define NCLASS 64
#define NCOMB 576
#define NPAD 640             // NCOMB padded to 5x128 col-tiles (zero cols)
#define NSKIP 320            // NHID + NCLASS (skip0 | skip1), bf16, biases folded
#define RRELU_SLOPE 0.2291666666666667f

typedef __attribute__((ext_vector_type(8))) short bf16x8;
typedef __attribute__((ext_vector_type(4))) float f32x4;

// async global->LDS, 16B per lane; dest = wave-uniform base + lane*16
#define GLOAD_LDS16(g, l)                                                      \
    __builtin_amdgcn_global_load_lds(                                          \
        (const __attribute__((address_space(1))) void*)(g),                    \
        (__attribute__((address_space(3))) void*)(l), 16, 0, 0)

__device__ __forceinline__ unsigned short f2bf(float f) {
    unsigned int x = __float_as_uint(f);
    unsigned int r = (x + 0x7fffu + ((x >> 16) & 1u)) >> 16;
    return (unsigned short)r;
}
__device__ __forceinline__ float bf2f(unsigned short u) {
    return __uint_as_float(((unsigned int)u) << 16);
}
__device__ __forceinline__ float bf_lo(unsigned int u) { return __uint_as_float(u << 16); }
__device__ __forceinline__ float bf_hi(unsigned int u) { return __uint_as_float(u & 0xffff0000u); }

// ---------------- mega-prep: all setup work + weight->out copies, one launch ----
// segments (flat item index):
#define S0 6400000            // cast x: float4 items (50000*512/4)
#define S1 7200000            // + edges (800000)
#define S2 7527680            // + Bt pack (640*512)
#define S3 7577681            // + rowptr (50001)
#define S4 7594065            // + w3t (16384)
#define S5 7594705            // + bias (640)
#define S6 7672529            // + weight copy, float4 items (77824)
#define PREP_BLOCKS ((S6 + 255) / 256)

__global__ __launch_bounds__(256)
void prep(const float* __restrict__ x, const int* __restrict__ erow,
          const int* __restrict__ ecol, const float* __restrict__ ev,
          const float* __restrict__ w1, const float* __restrict__ b1,
          const float* __restrict__ w2, const float* __restrict__ b2,
          const float* __restrict__ w3, const float* __restrict__ b3,
          const float* __restrict__ w4, const float* __restrict__ b4,
          unsigned short* __restrict__ xb, unsigned short* __restrict__ Bt,
          float* __restrict__ biasb, unsigned short* __restrict__ w3t,
          uint2* __restrict__ ep, int* __restrict__ rp,
          float* __restrict__ out) {
    int i = blockIdx.x * 256 + threadIdx.x;
    if (i >= S6) return;
    if (i < S0) {
        // cast x -> bf16 (4 elems)
        float4 v = ((const float4*)x)[i];
        ushort4 o;
        o.x = f2bf(v.x); o.y = f2bf(v.y); o.z = f2bf(v.z); o.w = f2bf(v.w);
        ((ushort4*)xb)[i] = o;
    } else if (i < S1) {
        int j = i - S0;
        uint2 e;
        e.x = (unsigned)ecol[j];
        e.y = __float_as_uint(ev[j]);
        ep[j] = e;
    } else if (i < S2) {
        int j = i - S1;
        int c = j >> 9;            // 0..639
        int k = j & 511;
        float v = 0.f;
        if (c < NHID)            v = w1[k * NHID + c];
        else if (c < 2 * NHID)   v = w2[k * NHID + (c - NHID)];
        else if (c < NCOMB)      v = w4[k * NCLASS + (c - 2 * NHID)];
        Bt[j] = f2bf(v);
    } else if (i < S3) {
        int n = i - S2;            // 0..50000
        int lo = 0, hi = N_EDGES;
        while (lo < hi) {
            int mid = (lo + hi) >> 1;
            if (erow[mid] < n) lo = mid + 1; else hi = mid;
        }
        rp[n] = lo;
    } else if (i < S4) {
        int j = i - S3;
        int c = j >> 8;            // NHID=256
        int k = j & 255;
        w3t[j] = f2bf(w3[k * NCLASS + c]);
    } else if (i < S5) {
        int b = i - S4;            // 0..639
        float v = 0.f;
        if (b >= NHID && b < 2 * NHID)      v = b1[b - NHID] + b2[b - NHID];
        else if (b >= 2 * NHID && b < NCOMB) v = b3[b - 2 * NHID] + b4[b - 2 * NHID];
        biasb[b] = v;
    } else {
        // weight tuple outputs: out[3.2M..] = w1|w2|w3|w4, float4 granularity
        int j = i - S5;            // 0..77823
        float4* o4 = (float4*)out;
        if (j < 32768)        o4[800000 + j] = ((const float4*)w1)[j];
        else if (j < 65536)   o4[832768 + (j - 32768)] = ((const float4*)w2)[j - 32768];
        else if (j < 69632)   o4[865536 + (j - 65536)] = ((const float4*)w3)[j - 65536];
        else                  o4[869632 + (j - 69632)] = ((const float4*)w4)[j - 69632];
    }
}

// ---------------- bf16 MFMA GEMM (templated col-tile) ----------------
// Tile 128 x BN, BK=64. global_load_lds(16B) staging, XOR-octet swizzle (no pad).
// LDS row = 64 bf16 = 128 B = 8 octets of 16 B; octet g of row r stored at slot g^(r&7).
// MODE 0 (BN=128, NPAD=640 cols): 1D grid, XCD-co-schedule swizzle — the 5
//   col-blocks of one row-panel get ids == same (mod 8) -> same XCD -> share L2
//   copy of the 131KB A-panel. cols<256 -> xw1b bf16; 256<=col<576 -> skipb (+bias)
// MODE 1 (BN=64): 2D grid; bf16 output to Cout [M, NC]
#define GBM 128
#define GBK 64
#define NCB0 5               // NPAD / 128 col-blocks in mode 0
#define NRP0 392             // row-panels in mode 0, padded to multiple of 8

template <int BN, int MODE>
__global__ __launch_bounds__(256)
void gemm_bf16(const unsigned short* __restrict__ A,   // [M,K] bf16 row-major
               const unsigned short* __restrict__ Bt,  // [*,K] bf16 row-major (B^T)
               const float* __restrict__ bias,
               unsigned short* __restrict__ Cout,
               unsigned short* __restrict__ skipb,
               unsigned short* __restrict__ xw1b,
               int M, int K, int NC) {
    constexpr int CF = BN / 32;               // col-frags per wave (4 or 2)
    __shared__ unsigned short As[GBM * GBK];  // 16 KB
    __shared__ unsigned short Bs[BN * GBK];   // 16 KB (128) / 8 KB (64)
    int row0, col0;
    if (MODE == 0) {
        // group of 8*NCB0 consecutive ids = 8 row-panels x NCB0 cols;
        // within group, id%8 = row-panel (=XCD), id/8 = col-block.
        int b = blockIdx.x;
        int g = b / (8 * NCB0);
        int w = b % (8 * NCB0);
        int r = g * 8 + (w & 7);
        int c = w >> 3;
        if (r * GBM >= M) return;           // padded tail
        row0 = r * GBM;
        col0 = c * BN;
    } else {
        col0 = blockIdx.x * BN;
        row0 = blockIdx.y * GBM;
    }
    const int tid  = threadIdx.x;
    const int lane = tid & 63;
    const int wave = tid >> 6;
    const int wr = (wave >> 1) * 64;
    const int wc = (wave & 1) * (BN / 2);
    const int lm = lane & 15;
    const int l4 = lane >> 4;       // 0..3 (k-octet within 32-k chunk)
    const int sw = lm & 7;          // row-based swizzle key for frag reads

    // staging lane decomposition: 1024 B per wave-issue = 8 rows x 8 octets
    const int sub  = lane >> 3;     // row within 8-row chunk
    const int slot = lane & 7;      // LDS octet slot this lane fills
    const int goct = slot ^ sub;    // global octet to fetch for that slot

    f32x4 acc[4][CF] = {};

    for (int k0 = 0; k0 < K; k0 += GBK) {
        // stage A: 16 chunks of 8 rows; 4 per wave
        #pragma unroll
        for (int p = 0; p < 4; ++p) {
            int chunk = wave * 4 + p;
            int gr = row0 + chunk * 8 + sub;
            if (gr > M - 1) gr = M - 1;     // clamp (dup rows only feed unsaved acc)
            GLOAD_LDS16(A + (size_t)gr * K + k0 + goct * 8, As + chunk * 512);
        }
        // stage B: BN/8 chunks of 8 rows; BN/32 per wave
        #pragma unroll
        for (int p = 0; p < BN / 32; ++p) {
            int chunk = wave * (BN / 32) + p;
            int rb = col0 + chunk * 8 + sub;
            GLOAD_LDS16(Bt + (size_t)rb * K + k0 + goct * 8, Bs + chunk * 512);
        }
        __syncthreads();

        #pragma unroll
        for (int kk8 = 0; kk8 < GBK / 8; kk8 += 4) {   // two 32-k steps
            const int so = ((kk8 + l4) ^ sw) * 8;
            bf16x8 bfr[CF];
            #pragma unroll
            for (int j = 0; j < CF; ++j)
                bfr[j] = *(const bf16x8*)(Bs + (wc + j * 16 + lm) * 64 + so);
            #pragma unroll
            for (int i = 0; i < 4; ++i) {
                bf16x8 af = *(const bf16x8*)(As + (wr + i * 16 + lm) * 64 + so);
                #pragma unroll
                for (int j = 0; j < CF; ++j)
                    acc[i][j] = __builtin_amdgcn_mfma_f32_16x16x32_bf16(af, bfr[j], acc[i][j], 0, 0, 0);
            }
        }
        __syncthreads();
    }

    // epilogue: C/D layout col=lane&15, row=(lane>>4)*4+reg
    #pragma unroll
    for (int i = 0; i < 4; ++i) {
        #pragma unroll
        for (int j = 0; j < CF; ++j) {
            int col = col0 + wc + j * 16 + lm;
            float bvv = (MODE == 0) ? bias[col] : 0.f;   // bias alloc'd NPAD, safe
            #pragma unroll
            for (int r = 0; r < 4; ++r) {
                int row = row0 + wr + i * 16 + l4 * 4 + r;
                if (row < M) {
                    float v = acc[i][j][r];
                    if (MODE == 0) {
                        if (col < NHID)       xw1b[(size_t)row * NHID + col] = f2bf(v);
                        else if (col < NCOMB) skipb[(size_t)row * NSKIP + (col - NHID)] = f2bf(v + bvv);
                    } else {
                        Cout[(size_t)row * NC + col] = f2bf(v);
                    }
                }
            }
        }
    }
}

// ---------------- SpMM1 + skip0(+b1+b2) + RReLU -> hb (bf16) ----------------
// one wave per node; lane covers 4 features (uint2 = 8B gather loads); 8-edge unroll
__global__ __launch_bounds__(256)
void spmm1_rrelu(const int* __restrict__ rp, const uint2* __restrict__ ep,
                 const unsigned short* __restrict__ xw1b,
                 const unsigned short* __restrict__ skipb,
                 unsigned short* __restrict__ hb, int n_nodes) {
    int n = blockIdx.x * 4 + (threadIdx.x >> 6);
    if (n >= n_nodes) return;
    int lane = threadIdx.x & 63;
    int f = lane * 4;
    int lo = rp[n], hi = rp[n + 1];
    float s0 = 0.f, s1 = 0.f, s2 = 0.f, s3 = 0.f;
    int e = lo;
    for (; e + 7 < hi; e += 8) {
        uint2 ed[8], p[8];
        #pragma unroll
        for (int q = 0; q < 8; ++q) ed[q] = ep[e + q];
        #pragma unroll
        for (int q = 0; q < 8; ++q)
            p[q] = *(const uint2*)(xw1b + (size_t)ed[q].x * NHID + f);
        #pragma unroll
        for (int q = 0; q < 8; ++q) {
            float v = __uint_as_float(ed[q].y);
            s0 += v * bf_lo(p[q].x);
            s1 += v * bf_hi(p[q].x);
            s2 += v * bf_lo(p[q].y);
            s3 += v * bf_hi(p[q].y);
        }
    }
    for (; e < hi; ++e) {
        uint2 ee = ep[e];
        float v = __uint_as_float(ee.y);
        uint2 p = *(const uint2*)(xw1b + (size_t)ee.x * NHID + f);
        s0 += v * bf_lo(p.x);
        s1 += v * bf_hi(p.x);
        s2 += v * bf_lo(p.y);
        s3 += v * bf_hi(p.y);
    }
    ushort4 sk = *(const ushort4*)(skipb + (size_t)n * NSKIP + f);
    float v0 = s0 + bf2f(sk.x), v1 = s1 + bf2f(sk.y);
    float v2 = s2 + bf2f(sk.z), v3 = s3 + bf2f(sk.w);
    v0 = (v0 >= 0.f) ? v0 : v0 * RRELU_SLOPE;
    v1 = (v1 >= 0.f) ? v1 : v1 * RRELU_SLOPE;
    v2 = (v2 >= 0.f) ? v2 : v2 * RRELU_SLOPE;
    v3 = (v3 >= 0.f) ? v3 : v3 * RRELU_SLOPE;
    ushort4 o;
    o.x = f2bf(v0); o.y = f2bf(v1); o.z = f2bf(v2); o.w = f2bf(v3);
    *(ushort4*)(hb + (size_t)n * NHID + f) = o;
}

// ---------------- SpMM2 + skip1(+b3+b4) -> out ----------------
// one wave per node; HALF-wave (32 lanes) per edge, lane covers 2 feats (uint load);
// 4-deep unroll per half = 8 edges in flight per wave
__global__ __launch_bounds__(256)
void spmm2_out(const int* __restrict__ rp, const uint2* __restrict__ ep,
               const unsigned short* __restrict__ hw3b,
               const unsigned short* __restrict__ skipb,
               float* __restrict__ out, int n_nodes) {
    int n = blockIdx.x * 4 + (threadIdx.x >> 6);
    if (n >= n_nodes) return;
    int lane = threadIdx.x & 63;
    int half = lane >> 5;
    int fl = (lane & 31) * 2;
    int lo = rp[n], hi = rp[n + 1];
    float s0 = 0.f, s1 = 0.f;
    int e = lo + half;
    for (; e + 6 < hi; e += 8) {
        uint2 e0 = ep[e], e1 = ep[e + 2], e2 = ep[e + 4], e3 = ep[e + 6];
        unsigned p0 = *(const unsigned*)(hw3b + (size_t)e0.x * NCLASS + fl);
        unsigned p1 = *(const unsigned*)(hw3b + (size_t)e1.x * NCLASS + fl);
        unsigned p2 = *(const unsigned*)(hw3b + (size_t)e2.x * NCLASS + fl);
        unsigned p3 = *(const unsigned*)(hw3b + (size_t)e3.x * NCLASS + fl);
        float v0 = __uint_as_float(e0.y), v1 = __uint_as_float(e1.y);
        float v2 = __uint_as_float(e2.y), v3 = __uint_as_float(e3.y);
        s0 += v0 * bf_lo(p0) + v1 * bf_lo(p1) + v2 * bf_lo(p2) + v3 * bf_lo(p3);
        s1 += v0 * bf_hi(p0) + v1 * bf_hi(p1) + v2 * bf_hi(p2) + v3 * bf_hi(p3);
    }
    for (; e < hi; e += 2) {
        uint2 ee = ep[e];
        unsigned p = *(const unsigned*)(hw3b + (size_t)ee.x * NCLASS + fl);
        float v = __uint_as_float(ee.y);
        s0 += v * bf_lo(p);
        s1 += v * bf_hi(p);
    }
    s0 += __shfl_xor(s0, 32);
    s1 += __shfl_xor(s1, 32);
    if (half == 0) {
        unsigned sv = *(const unsigned*)(skipb + (size_t)n * NSKIP + NHID + fl);
        float2 o;
        o.x = s0 + bf_lo(sv);
        o.y = s1 + bf_hi(sv);
        *(float2*)(out + (size_t)n * NCLASS + fl) = o;
    }
}

extern "C" void kernel_launch(void* const* d_in, const int* in_sizes, int n_in,
                              void* d_out, int out_size, void* d_ws, size_t ws_size,
                              hipStream_t stream) {
    const float* x    = (const float*)d_in[0];
    const int*   erow = (const int*)d_in[1];
    const int*   ecol = (const int*)d_in[2];
    const float* ev   = (const float*)d_in[3];
    const float* w1   = (const float*)d_in[4];
    const float* b1   = (const float*)d_in[5];
    const float* w2   = (const float*)d_in[6];
    const float* b2   = (const float*)d_in[7];
    const float* w3   = (const float*)d_in[8];
    const float* b3   = (const float*)d_in[9];
    const float* w4   = (const float*)d_in[10];
    const float* b4   = (const float*)d_in[11];
    float* out = (float*)d_out;

    char* ws = (char*)d_ws;
    size_t off = 0;
    auto alloc = [&](size_t bytes) -> void* {
        off = (off + 255) & ~(size_t)255;
        void* p = ws + off;
        off += bytes;
        return p;
    };

    unsigned short* xb    = (unsigned short*)alloc((size_t)N_NODES * NFEAT * 2);
    unsigned short* Bt    = (unsigned short*)alloc((size_t)NFEAT * NPAD * 2);
    float*          biasb = (float*)alloc(NPAD * 4);
    unsigned short* xw1b  = (unsigned short*)alloc((size_t)N_NODES * NHID * 2);
    unsigned short* skipb = (unsigned short*)alloc((size_t)N_NODES * NSKIP * 2);
    unsigned short* hb    = (unsigned short*)alloc((size_t)N_NODES * NHID * 2);
    unsigned short* w3t   = (unsigned short*)alloc((size_t)NHID * NCLASS * 2);
    unsigned short* hw3b  = (unsigned short*)alloc((size_t)N_NODES * NCLASS * 2);
    int*            rp    = (int*)alloc((size_t)(N_NODES + 1) * 4);
    uint2*          ep    = (uint2*)alloc((size_t)N_EDGES * 8);

    // 1) all prep in one launch (casts, packs, rowptr, edge pack, weight->out copies)
    prep<<<PREP_BLOCKS, 256, 0, stream>>>(x, erow, ecol, ev, w1, b1, w2, b2, w3, b3,
                                          w4, b4, xb, Bt, biasb, w3t, ep, rp, out);

    // 2) fused GEMM: xb @ [w1|w2|w4|pad] -> xw1b (bf16) | skipb (bf16, +bias)
    gemm_bf16<128, 0><<<NRP0 * NCB0, 256, 0, stream>>>(xb, Bt, biasb, nullptr, skipb, xw1b,
                                                       N_NODES, NFEAT, NPAD);

    // 3) spmm(xw1) + skip0 -> rrelu -> hb (bf16)
    spmm1_rrelu<<<(N_NODES + 3) / 4, 256, 0, stream>>>(rp, ep, xw1b, skipb, hb, N_NODES);

    // 4) hw3b = hb @ w3 (bf16 out)
    dim3 g2(NCLASS / 64, (N_NODES + GBM - 1) / GBM);
    gemm_bf16<64, 1><<<g2, 256, 0, stream>>>(hb, w3t, nullptr, hw3b, nullptr, nullptr,
                                             N_NODES, NHID, NCLASS);

    // 5) out = spmm(hw3) + skip1
    spmm2_out<<<(N_NODES + 3) / 4, 256, 0, stream>>>(rp, ep, hw3b, skipb, out, N_NODES);
}

// Round 7
// 311.544 us; speedup vs baseline: 1.9470x; 1.0912x over previous
//
#include <hip/hip_runtime.h>

// Problem constants
#define N_NODES 50000
#define N_EDGES 800000
#define NFEAT 512
#define NHID 256
#define NCLASS 64
#define NCOMB 576
#define NPAD 640             // NCOMB padded to 5x128 col-tiles (zero cols)
#define NSKIP 320            // NHID + NCLASS (skip0 | skip1), bf16, biases folded
#define RRELU_SLOPE 0.2291666666666667f

typedef __attribute__((ext_vector_type(8))) short bf16x8;
typedef __attribute__((ext_vector_type(4))) float f32x4;
typedef __attribute__((ext_vector_type(2))) float f32x2;

// async global->LDS, 16B per lane; dest = wave-uniform base + lane*16
#define GLOAD_LDS16(g, l)                                                      \
    __builtin_amdgcn_global_load_lds(                                          \
        (const __attribute__((address_space(1))) void*)(g),                    \
        (__attribute__((address_space(3))) void*)(l), 16, 0, 0)

__device__ __forceinline__ unsigned short f2bf(float f) {
    unsigned int x = __float_as_uint(f);
    unsigned int r = (x + 0x7fffu + ((x >> 16) & 1u)) >> 16;
    return (unsigned short)r;
}
__device__ __forceinline__ float bf2f(unsigned short u) {
    return __uint_as_float(((unsigned int)u) << 16);
}
__device__ __forceinline__ float bf_lo(unsigned int u) { return __uint_as_float(u << 16); }
__device__ __forceinline__ float bf_hi(unsigned int u) { return __uint_as_float(u & 0xffff0000u); }
// fp32 -> OCP e4m3 byte (RNE, saturating)
__device__ __forceinline__ unsigned char f2fp8(float v) {
    return (unsigned char)__builtin_amdgcn_cvt_pk_fp8_f32(v, v, 0, false);
}

// ---------------- mega-prep: all setup work + weight->out copies, one launch ----
#define S0 6400000            // cast x: float4 items (50000*512/4)
#define S1 7200000            // + edges (800000)
#define S2 7527680            // + Bt pack (640*512)
#define S3 7577681            // + rowptr (50001)
#define S4 7594065            // + w3t (16384)
#define S5 7594705            // + bias (640)
#define S6 7672529            // + weight copy, float4 items (77824)
#define PREP_BLOCKS ((S6 + 255) / 256)

__global__ __launch_bounds__(256)
void prep(const float* __restrict__ x, const int* __restrict__ erow,
          const int* __restrict__ ecol, const float* __restrict__ ev,
          const float* __restrict__ w1, const float* __restrict__ b1,
          const float* __restrict__ w2, const float* __restrict__ b2,
          const float* __restrict__ w3, const float* __restrict__ b3,
          const float* __restrict__ w4, const float* __restrict__ b4,
          unsigned short* __restrict__ xb, unsigned short* __restrict__ Bt,
          float* __restrict__ biasb, unsigned short* __restrict__ w3t,
          uint2* __restrict__ ep, int* __restrict__ rp,
          float* __restrict__ out) {
    int i = blockIdx.x * 256 + threadIdx.x;
    if (i >= S6) return;
    if (i < S0) {
        float4 v = ((const float4*)x)[i];
        ushort4 o;
        o.x = f2bf(v.x); o.y = f2bf(v.y); o.z = f2bf(v.z); o.w = f2bf(v.w);
        ((ushort4*)xb)[i] = o;
    } else if (i < S1) {
        int j = i - S0;
        uint2 e;
        e.x = (unsigned)ecol[j];
        e.y = __float_as_uint(ev[j]);
        ep[j] = e;
    } else if (i < S2) {
        int j = i - S1;
        int c = j >> 9;            // 0..639
        int k = j & 511;
        float v = 0.f;
        if (c < NHID)            v = w1[k * NHID + c];
        else if (c < 2 * NHID)   v = w2[k * NHID + (c - NHID)];
        else if (c < NCOMB)      v = w4[k * NCLASS + (c - 2 * NHID)];
        Bt[j] = f2bf(v);
    } else if (i < S3) {
        int n = i - S2;            // 0..50000
        int lo = 0, hi = N_EDGES;
        while (lo < hi) {
            int mid = (lo + hi) >> 1;
            if (erow[mid] < n) lo = mid + 1; else hi = mid;
        }
        rp[n] = lo;
    } else if (i < S4) {
        int j = i - S3;
        int c = j >> 8;            // NHID=256
        int k = j & 255;
        w3t[j] = f2bf(w3[k * NCLASS + c]);
    } else if (i < S5) {
        int b = i - S4;            // 0..639
        float v = 0.f;
        if (b >= NHID && b < 2 * NHID)       v = b1[b - NHID] + b2[b - NHID];
        else if (b >= 2 * NHID && b < NCOMB) v = b3[b - 2 * NHID] + b4[b - 2 * NHID];
        biasb[b] = v;
    } else {
        int j = i - S5;            // 0..77823
        float4* o4 = (float4*)out;
        if (j < 32768)        o4[800000 + j] = ((const float4*)w1)[j];
        else if (j < 65536)   o4[832768 + (j - 32768)] = ((const float4*)w2)[j - 32768];
        else if (j < 69632)   o4[865536 + (j - 65536)] = ((const float4*)w3)[j - 65536];
        else                  o4[869632 + (j - 69632)] = ((const float4*)w4)[j - 69632];
    }
}

// ---------------- bf16 MFMA GEMM (templated col-tile) ----------------
// Tile 128 x BN, BK=64. global_load_lds(16B) staging, XOR-octet swizzle (no pad).
// MODE 0 (BN=128, NPAD=640 cols): XCD-co-schedule swizzle (5 col-blocks of a
//   row-panel land on one XCD, share its L2 A-panel copy).
//   cols<256 -> xw1 fp8; 256<=col<576 -> skipb bf16 (+bias)
// MODE 1 (BN=64): 2D grid; fp8 output to C8 [M, NC]
// __launch_bounds__(256,4): cap unified regs at 128 (64 acc + ~60 live) ->
//   4 waves/SIMD (round-6 ran 144 regs -> 2 waves/SIMD, occupancy 23.5%)
#define GBM 128
#define GBK 64
#define NCB0 5               // NPAD / 128 col-blocks in mode 0
#define NRP0 392             // row-panels in mode 0, padded to multiple of 8

template <int BN, int MODE>
__global__ __launch_bounds__(256, 4)
void gemm_bf16(const unsigned short* __restrict__ A,   // [M,K] bf16 row-major
               const unsigned short* __restrict__ Bt,  // [*,K] bf16 row-major (B^T)
               const float* __restrict__ bias,
               unsigned char* __restrict__ C8,         // fp8 dest (mode0: xw1, mode1: hw3)
               unsigned short* __restrict__ skipb,     // mode 0 only
               int M, int K, int NC) {
    constexpr int CF = BN / 32;               // col-frags per wave (4 or 2)
    __shared__ unsigned short As[GBM * GBK];  // 16 KB
    __shared__ unsigned short Bs[BN * GBK];   // 16 KB (128) / 8 KB (64)
    int row0, col0;
    if (MODE == 0) {
        int b = blockIdx.x;
        int g = b / (8 * NCB0);
        int w = b % (8 * NCB0);
        int r = g * 8 + (w & 7);
        int c = w >> 3;
        if (r * GBM >= M) return;           // padded tail
        row0 = r * GBM;
        col0 = c * BN;
    } else {
        col0 = blockIdx.x * BN;
        row0 = blockIdx.y * GBM;
    }
    const int tid  = threadIdx.x;
    const int lane = tid & 63;
    const int wave = tid >> 6;
    const int wr = (wave >> 1) * 64;
    const int wc = (wave & 1) * (BN / 2);
    const int lm = lane & 15;
    const int l4 = lane >> 4;       // 0..3 (k-octet within 32-k chunk)
    const int sw = lm & 7;          // row-based swizzle key for frag reads

    // staging lane decomposition: 1024 B per wave-issue = 8 rows x 8 octets
    const int sub  = lane >> 3;     // row within 8-row chunk
    const int slot = lane & 7;      // LDS octet slot this lane fills
    const int goct = slot ^ sub;    // global octet to fetch for that slot

    f32x4 acc[4][CF] = {};

    for (int k0 = 0; k0 < K; k0 += GBK) {
        #pragma unroll
        for (int p = 0; p < 4; ++p) {
            int chunk = wave * 4 + p;
            int gr = row0 + chunk * 8 + sub;
            if (gr > M - 1) gr = M - 1;     // clamp (dup rows only feed unsaved acc)
            GLOAD_LDS16(A + (size_t)gr * K + k0 + goct * 8, As + chunk * 512);
        }
        #pragma unroll
        for (int p = 0; p < BN / 32; ++p) {
            int chunk = wave * (BN / 32) + p;
            int rb = col0 + chunk * 8 + sub;
            GLOAD_LDS16(Bt + (size_t)rb * K + k0 + goct * 8, Bs + chunk * 512);
        }
        __syncthreads();

        #pragma unroll
        for (int kk8 = 0; kk8 < GBK / 8; kk8 += 4) {   // two 32-k steps
            const int so = ((kk8 + l4) ^ sw) * 8;
            bf16x8 bfr[CF];
            #pragma unroll
            for (int j = 0; j < CF; ++j)
                bfr[j] = *(const bf16x8*)(Bs + (wc + j * 16 + lm) * 64 + so);
            #pragma unroll
            for (int i = 0; i < 4; ++i) {
                bf16x8 af = *(const bf16x8*)(As + (wr + i * 16 + lm) * 64 + so);
                #pragma unroll
                for (int j = 0; j < CF; ++j)
                    acc[i][j] = __builtin_amdgcn_mfma_f32_16x16x32_bf16(af, bfr[j], acc[i][j], 0, 0, 0);
            }
        }
        __syncthreads();
    }

    // epilogue: C/D layout col=lane&15, row=(lane>>4)*4+reg
    #pragma unroll
    for (int i = 0; i < 4; ++i) {
        #pragma unroll
        for (int j = 0; j < CF; ++j) {
            int col = col0 + wc + j * 16 + lm;
            float bvv = (MODE == 0) ? bias[col] : 0.f;   // bias alloc'd NPAD, safe
            #pragma unroll
            for (int r = 0; r < 4; ++r) {
                int row = row0 + wr + i * 16 + l4 * 4 + r;
                if (row < M) {
                    float v = acc[i][j][r];
                    if (MODE == 0) {
                        if (col < NHID)       C8[(size_t)row * NHID + col] = f2fp8(v);
                        else if (col < NCOMB) skipb[(size_t)row * NSKIP + (col - NHID)] = f2bf(v + bvv);
                    } else {
                        C8[(size_t)row * NC + col] = f2fp8(v);
                    }
                }
            }
        }
    }
}

// ---------------- SpMM1 + skip0(+b1+b2) + RReLU -> hb (bf16) ----------------
// one wave per node; lane covers 4 features (fp8 dword gather); 8-edge unroll
__global__ __launch_bounds__(256)
void spmm1_rrelu(const int* __restrict__ rp, const uint2* __restrict__ ep,
                 const unsigned char* __restrict__ xw1q,
                 const unsigned short* __restrict__ skipb,
                 unsigned short* __restrict__ hb, int n_nodes) {
    int n = blockIdx.x * 4 + (threadIdx.x >> 6);
    if (n >= n_nodes) return;
    int lane = threadIdx.x & 63;
    int f = lane * 4;
    int lo = rp[n], hi = rp[n + 1];
    float s0 = 0.f, s1 = 0.f, s2 = 0.f, s3 = 0.f;
    int e = lo;
    for (; e + 7 < hi; e += 8) {
        uint2 ed[8];
        unsigned p[8];
        #pragma unroll
        for (int q = 0; q < 8; ++q) ed[q] = ep[e + q];
        #pragma unroll
        for (int q = 0; q < 8; ++q)
            p[q] = *(const unsigned*)(xw1q + (size_t)ed[q].x * NHID + f);
        #pragma unroll
        for (int q = 0; q < 8; ++q) {
            float v = __uint_as_float(ed[q].y);
            f32x2 ab = __builtin_amdgcn_cvt_pk_f32_fp8((int)p[q], false);
            f32x2 cd = __builtin_amdgcn_cvt_pk_f32_fp8((int)p[q], true);
            s0 += v * ab.x;
            s1 += v * ab.y;
            s2 += v * cd.x;
            s3 += v * cd.y;
        }
    }
    for (; e < hi; ++e) {
        uint2 ee = ep[e];
        float v = __uint_as_float(ee.y);
        unsigned p = *(const unsigned*)(xw1q + (size_t)ee.x * NHID + f);
        f32x2 ab = __builtin_amdgcn_cvt_pk_f32_fp8((int)p, false);
        f32x2 cd = __builtin_amdgcn_cvt_pk_f32_fp8((int)p, true);
        s0 += v * ab.x;
        s1 += v * ab.y;
        s2 += v * cd.x;
        s3 += v * cd.y;
    }
    ushort4 sk = *(const ushort4*)(skipb + (size_t)n * NSKIP + f);
    float v0 = s0 + bf2f(sk.x), v1 = s1 + bf2f(sk.y);
    float v2 = s2 + bf2f(sk.z), v3 = s3 + bf2f(sk.w);
    v0 = (v0 >= 0.f) ? v0 : v0 * RRELU_SLOPE;
    v1 = (v1 >= 0.f) ? v1 : v1 * RRELU_SLOPE;
    v2 = (v2 >= 0.f) ? v2 : v2 * RRELU_SLOPE;
    v3 = (v3 >= 0.f) ? v3 : v3 * RRELU_SLOPE;
    ushort4 o;
    o.x = f2bf(v0); o.y = f2bf(v1); o.z = f2bf(v2); o.w = f2bf(v3);
    *(ushort4*)(hb + (size_t)n * NHID + f) = o;
}

// ---------------- SpMM2 + skip1(+b3+b4) -> out ----------------
// one wave per node; QUARTER-wave (16 lanes) per edge, lane covers 4 fp8 feats;
// 4 edges concurrent per wave, 2-deep unroll = 8 in flight; shfl_xor(16,32) merge
__global__ __launch_bounds__(256)
void spmm2_out(const int* __restrict__ rp, const uint2* __restrict__ ep,
               const unsigned char* __restrict__ hw3q,
               const unsigned short* __restrict__ skipb,
               float* __restrict__ out, int n_nodes) {
    int n = blockIdx.x * 4 + (threadIdx.x >> 6);
    if (n >= n_nodes) return;
    int lane = threadIdx.x & 63;
    int q = lane >> 4;         // quarter 0..3 = edge slot
    int l = lane & 15;
    int f = l * 4;             // feature base
    int lo = rp[n], hi = rp[n + 1];
    float s0 = 0.f, s1 = 0.f, s2 = 0.f, s3 = 0.f;
    int e = lo + q;
    for (; e + 4 < hi; e += 8) {
        uint2 ea = ep[e], eb = ep[e + 4];
        unsigned pa = *(const unsigned*)(hw3q + (size_t)ea.x * NCLASS + f);
        unsigned pb = *(const unsigned*)(hw3q + (size_t)eb.x * NCLASS + f);
        float va = __uint_as_float(ea.y), vb = __uint_as_float(eb.y);
        f32x2 a0 = __builtin_amdgcn_cvt_pk_f32_fp8((int)pa, false);
        f32x2 a1 = __builtin_amdgcn_cvt_pk_f32_fp8((int)pa, true);
        f32x2 b0 = __builtin_amdgcn_cvt_pk_f32_fp8((int)pb, false);
        f32x2 b1 = __builtin_amdgcn_cvt_pk_f32_fp8((int)pb, true);
        s0 += va * a0.x + vb * b0.x;
        s1 += va * a0.y + vb * b0.y;
        s2 += va * a1.x + vb * b1.x;
        s3 += va * a1.y + vb * b1.y;
    }
    for (; e < hi; e += 4) {
        uint2 ee = ep[e];
        unsigned p = *(const unsigned*)(hw3q + (size_t)ee.x * NCLASS + f);
        float v = __uint_as_float(ee.y);
        f32x2 ab = __builtin_amdgcn_cvt_pk_f32_fp8((int)p, false);
        f32x2 cd = __builtin_amdgcn_cvt_pk_f32_fp8((int)p, true);
        s0 += v * ab.x;
        s1 += v * ab.y;
        s2 += v * cd.x;
        s3 += v * cd.y;
    }
    s0 += __shfl_xor(s0, 16); s0 += __shfl_xor(s0, 32);
    s1 += __shfl_xor(s1, 16); s1 += __shfl_xor(s1, 32);
    s2 += __shfl_xor(s2, 16); s2 += __shfl_xor(s2, 32);
    s3 += __shfl_xor(s3, 16); s3 += __shfl_xor(s3, 32);
    if (q == 0) {
        uint2 sv = *(const uint2*)(skipb + (size_t)n * NSKIP + NHID + f);
        float4 o;
        o.x = s0 + bf_lo(sv.x);
        o.y = s1 + bf_hi(sv.x);
        o.z = s2 + bf_lo(sv.y);
        o.w = s3 + bf_hi(sv.y);
        *(float4*)(out + (size_t)n * NCLASS + f) = o;
    }
}

extern "C" void kernel_launch(void* const* d_in, const int* in_sizes, int n_in,
                              void* d_out, int out_size, void* d_ws, size_t ws_size,
                              hipStream_t stream) {
    const float* x    = (const float*)d_in[0];
    const int*   erow = (const int*)d_in[1];
    const int*   ecol = (const int*)d_in[2];
    const float* ev   = (const float*)d_in[3];
    const float* w1   = (const float*)d_in[4];
    const float* b1   = (const float*)d_in[5];
    const float* w2   = (const float*)d_in[6];
    const float* b2   = (const float*)d_in[7];
    const float* w3   = (const float*)d_in[8];
    const float* b3   = (const float*)d_in[9];
    const float* w4   = (const float*)d_in[10];
    const float* b4   = (const float*)d_in[11];
    float* out = (float*)d_out;

    char* ws = (char*)d_ws;
    size_t off = 0;
    auto alloc = [&](size_t bytes) -> void* {
        off = (off + 255) & ~(size_t)255;
        void* p = ws + off;
        off += bytes;
        return p;
    };

    unsigned short* xb    = (unsigned short*)alloc((size_t)N_NODES * NFEAT * 2);
    unsigned short* Bt    = (unsigned short*)alloc((size_t)NFEAT * NPAD * 2);
    float*          biasb = (float*)alloc(NPAD * 4);
    unsigned char*  xw1q  = (unsigned char*)alloc((size_t)N_NODES * NHID);
    unsigned short* skipb = (unsigned short*)alloc((size_t)N_NODES * NSKIP * 2);
    unsigned short* hb    = (unsigned short*)alloc((size_t)N_NODES * NHID * 2);
    unsigned short* w3t   = (unsigned short*)alloc((size_t)NHID * NCLASS * 2);
    unsigned char*  hw3q  = (unsigned char*)alloc((size_t)N_NODES * NCLASS);
    int*            rp    = (int*)alloc((size_t)(N_NODES + 1) * 4);
    uint2*          ep    = (uint2*)alloc((size_t)N_EDGES * 8);

    // 1) all prep in one launch
    prep<<<PREP_BLOCKS, 256, 0, stream>>>(x, erow, ecol, ev, w1, b1, w2, b2, w3, b3,
                                          w4, b4, xb, Bt, biasb, w3t, ep, rp, out);

    // 2) fused GEMM: xb @ [w1|w2|w4|pad] -> xw1q (fp8) | skipb (bf16, +bias)
    gemm_bf16<128, 0><<<NRP0 * NCB0, 256, 0, stream>>>(xb, Bt, biasb, xw1q, skipb,
                                                       N_NODES, NFEAT, NPAD);

    // 3) spmm(xw1) + skip0 -> rrelu -> hb (bf16)
    spmm1_rrelu<<<(N_NODES + 3) / 4, 256, 0, stream>>>(rp, ep, xw1q, skipb, hb, N_NODES);

    // 4) hw3q = hb @ w3 (fp8 out)
    dim3 g2(NCLASS / 64, (N_NODES + GBM - 1) / GBM);
    gemm_bf16<64, 1><<<g2, 256, 0, stream>>>(hb, w3t, nullptr, hw3q, nullptr,
                                             N_NODES, NHID, NCLASS);

    // 5) out = spmm(hw3) + skip1
    spmm2_out<<<(N_NODES + 3) / 4, 256, 0, stream>>>(rp, ep, hw3q, skipb, out, N_NODES);
}